// Round 8
// baseline (5657.305 us; speedup 1.0000x reference)
//
#include <hip/hip_runtime.h>
#include <math.h>

#define D_MODEL 768
#define T_SEQ   1024
#define BATCH   4
#define NCH     7
#define ROWS    4096            // BATCH*T_SEQ
#define KM      (NCH * D_MODEL) // 5376
#define SEQ_NBLK 768            // seq chain: exactly 3 blocks/CU on 256 CUs
#define BAR_STRIDE 32           // 128B cacheline stride (in unsigned units)
#define NGO 12                  // go-flag groups (64 blocks each)

typedef unsigned short u16;
typedef __attribute__((ext_vector_type(8))) short bh8;   // 8 x bf16
typedef __attribute__((ext_vector_type(4))) float f32x4;

__device__ __forceinline__ u16 f2bf(float f) {
    union { float f; unsigned u; } v; v.f = f;
    return (u16)((v.u + 0x7fffu + ((v.u >> 16) & 1u)) >> 16);  // RNE
}
__device__ __forceinline__ float bf2f(u16 b) {
    union { unsigned u; float f; } v; v.u = ((unsigned)b) << 16;
    return v.f;
}
__device__ __forceinline__ float wred_sum(float v) {
    #pragma unroll
    for (int o = 32; o; o >>= 1) v += __shfl_down(v, o, 64);
    return v;
}
__device__ __forceinline__ float wred_max(float v) {
    #pragma unroll
    for (int o = 32; o; o >>= 1) v = fmaxf(v, __shfl_down(v, o, 64));
    return v;
}
__device__ __forceinline__ float chamber_mask(int i) {
    float slope = 8.0f * 7.0f / 2000.0f;
    return 1.0f / (1.0f + __expf(-slope * (4000.0f - 2000.0f * (i + 0.5f) / 7.0f)));
}

#define GLD16(g, l) __builtin_amdgcn_global_load_lds( \
    (const __attribute__((address_space(1))) void*)(g), \
    (__attribute__((address_space(3))) void*)(l), 16, 0, 0)

// XCD-aware swizzle (identity when N not divisible by 8).
__device__ __forceinline__ int xcd_swizzle(int gflat, int Ntot) {
    if ((Ntot & 7) == 0) {
        int chunk = Ntot >> 3;
        gflat = (gflat & 7) * chunk + (gflat >> 3);
    }
    return gflat;
}

// LDS slot swizzle — 64-tile paths ONLY (A/B: helps LDS-read-bound gemm64,
// hurts stage-bound gemm128 by ~10%).
__device__ __forceinline__ int slot_f(int row) { return (row >> 1) & 3; }

// ---------------------------------------------------------------------------
// Flag-array grid barrier (all-report / one-scans / broadcast).
// R7 lesson: single-counter barrier = 768 RMWs serialized on one line with
// cross-XCD ping-pong (~130 us/barrier). Here: arrival = 768 parallel
// release-stores to distinct 128B lines; wave 0 of block 0 scans (reads
// pipeline, no ownership transfer); 12 per-group go-lines broadcast.
// Monotonic generations: a block arriving at gen+1 satisfies a gen scan.
// arrive/go zeroed per replay (hipMemsetAsync inside capture).
// ---------------------------------------------------------------------------
__device__ __forceinline__ void grid_bar(unsigned* arrive, unsigned* go, int gen)
{
    __syncthreads();
    int tid = threadIdx.x;
    if (tid == 0) {
        __threadfence();
        __hip_atomic_store(&arrive[blockIdx.x * BAR_STRIDE], (unsigned)gen,
                           __ATOMIC_RELEASE, __HIP_MEMORY_SCOPE_AGENT);
    }
    if (blockIdx.x == 0) {
        if (tid < 64) {                    // wave 0 scans all 768 flags
            for (;;) {
                bool ok = true;
                #pragma unroll
                for (int k = 0; k < 12; k++) {
                    int idx = tid + k * 64;
                    ok &= (__hip_atomic_load(&arrive[idx * BAR_STRIDE],
                                             __ATOMIC_ACQUIRE,
                                             __HIP_MEMORY_SCOPE_AGENT)
                           >= (unsigned)gen);
                }
                if (__all(ok)) break;
                __builtin_amdgcn_s_sleep(1);
            }
            __threadfence();
            if (tid < NGO)
                __hip_atomic_store(&go[tid * BAR_STRIDE], (unsigned)gen,
                                   __ATOMIC_RELEASE, __HIP_MEMORY_SCOPE_AGENT);
        }
    } else {
        if (tid == 0) {
            while (__hip_atomic_load(&go[(blockIdx.x >> 6) * BAR_STRIDE],
                                     __ATOMIC_ACQUIRE,
                                     __HIP_MEMORY_SCOPE_AGENT) < (unsigned)gen)
                __builtin_amdgcn_s_sleep(8);
            __threadfence();
        }
    }
    __syncthreads();
}

// ---------------------------------------------------------------------------
// 128x128-tile NT GEMM: C = alpha * A[M,K] * B[N,K]^T  (bf16 in)
// K=64 per barrier as TWO independent BK=32 panels; XCD tile swizzle.
// mode: 0 f32 store, 1 bf16 store, 3 f16 store
// kss/klen: K slice per bz1 (merge partials). All K extents multiple of 64.
// ---------------------------------------------------------------------------
__global__ __launch_bounds__(256)
void gemm_nt_kernel(const u16* __restrict__ A, const u16* __restrict__ B,
                    void* __restrict__ Cv,
                    int K, int lda, int ldb, int ldc,
                    long long sA1, long long sA2, long long sB1, long long sB2,
                    long long sC1, long long sC2, int zm,
                    float alpha, int mode, int causal_skip, int causal_k,
                    int kss, int klen)
{
    int gx = gridDim.x, gy = gridDim.y;
    int Ntot = gx * gy * gridDim.z;
    int gflat = xcd_swizzle(blockIdx.x + gx * (blockIdx.y + gy * blockIdx.z), Ntot);
    int bn = gflat % gx;
    int rest = gflat / gx;
    int bm = rest % gy;
    int bz = rest / gy;
    if (causal_skip && bn > bm) return;
    int bz1 = bz % zm, bz2 = bz / zm;

    const u16* Ab = A + bz1 * sA1 + bz2 * sA2 + (long long)(bm * 128) * lda;
    const u16* Bb = B + bz1 * sB1 + bz2 * sB2 + (long long)(bn * 128) * ldb;

    __shared__ u16 sm[4 * 128 * 32];   // 32 KB: A0|B0|A1|B1 panels
    u16* Al0 = sm;
    u16* Bl0 = sm + 128 * 32;
    u16* Al1 = sm + 2 * 128 * 32;
    u16* Bl1 = sm + 3 * 128 * 32;

    int tid  = threadIdx.x;
    int lane = tid & 63;
    int wave = tid >> 6;
    int wm = wave >> 1, wn = wave & 1;

    int k_begin = kss ? bz1 * kss : 0;
    int k_end   = klen ? (k_begin + klen) : K;
    if (causal_k) k_end = min(k_end, (bm + 1) * 128);

    f32x4 acc[4][4];
    #pragma unroll
    for (int i = 0; i < 4; i++)
        #pragma unroll
        for (int j = 0; j < 4; j++)
            acc[i][j] = (f32x4){0.f, 0.f, 0.f, 0.f};

    int srow = lane >> 2;
    int skq  = (lane & 3) * 8;
    int fm   = lane & 15;
    int fk   = (lane >> 4) * 8;

    for (int k0 = k_begin; k0 < k_end; k0 += 64) {
        __syncthreads();
        #pragma unroll
        for (int r = 0; r < 2; r++) {
            int row = r * 64 + wave * 16 + srow;
            long long ra = (long long)row * lda + k0 + skq;
            long long rb2 = (long long)row * ldb + k0 + skq;
            GLD16(Ab + ra,       Al0 + row * 32 + skq);
            GLD16(Bb + rb2,      Bl0 + row * 32 + skq);
            GLD16(Ab + ra + 32,  Al1 + row * 32 + skq);
            GLD16(Bb + rb2 + 32, Bl1 + row * 32 + skq);
        }
        __syncthreads();

        #pragma unroll
        for (int p = 0; p < 2; p++) {
            const u16* Al = p ? Al1 : Al0;
            const u16* Bl = p ? Bl1 : Bl0;
            bh8 af[4], bf[4];
            #pragma unroll
            for (int i = 0; i < 4; i++)
                af[i] = *(const bh8*)(Al + (wm * 64 + i * 16 + fm) * 32 + fk);
            #pragma unroll
            for (int j = 0; j < 4; j++)
                bf[j] = *(const bh8*)(Bl + (wn * 64 + j * 16 + fm) * 32 + fk);
            #pragma unroll
            for (int i = 0; i < 4; i++)
                #pragma unroll
                for (int j = 0; j < 4; j++)
                    acc[i][j] = __builtin_amdgcn_mfma_f32_16x16x32_bf16(af[i], bf[j], acc[i][j], 0, 0, 0);
        }
    }

    int rbase = bm * 128 + wm * 64 + (lane >> 4) * 4;
    int cbase = bn * 128 + wn * 64 + (lane & 15);
    long long zoff = bz1 * sC1 + bz2 * sC2;
    if (mode == 1) {
        u16* C = (u16*)Cv + zoff;
        #pragma unroll
        for (int i = 0; i < 4; i++)
            #pragma unroll
            for (int j = 0; j < 4; j++)
                #pragma unroll
                for (int r = 0; r < 4; r++)
                    C[(long long)(rbase + i * 16 + r) * ldc + cbase + j * 16] = f2bf(acc[i][j][r] * alpha);
    } else if (mode == 3) {
        u16* C = (u16*)Cv + zoff;
        #pragma unroll
        for (int i = 0; i < 4; i++)
            #pragma unroll
            for (int j = 0; j < 4; j++)
                #pragma unroll
                for (int r = 0; r < 4; r++) {
                    union { _Float16 h; u16 u; } cv;
                    cv.h = (_Float16)(acc[i][j][r] * alpha);
                    C[(long long)(rbase + i * 16 + r) * ldc + cbase + j * 16] = cv.u;
                }
    } else {
        float* C = (float*)Cv + zoff;
        #pragma unroll
        for (int i = 0; i < 4; i++)
            #pragma unroll
            for (int j = 0; j < 4; j++)
                #pragma unroll
                for (int r = 0; r < 4; r++)
                    C[(long long)(rbase + i * 16 + r) * ldc + cbase + j * 16] = acc[i][j][r] * alpha;
    }
}

// ---------------------------------------------------------------------------
// 64x64-tile NT GEMM — K=128 per barrier as FOUR BK=32 panels (2-panel tail).
// XCD tile swizzle + LDS slot swizzle. tri: compact triangular launch.
// lptrev: heavy causal-K tiles first. (Round-5 version, verbatim — par branch.)
// mode: 0 f32, 1 bf16, 3 f16, 5 par PV+delta, 6 seq PV+delta.
// ---------------------------------------------------------------------------
__global__ __launch_bounds__(256)
void gemm64_nt_kernel(const u16* __restrict__ A, const u16* __restrict__ B,
                      void* __restrict__ Cv,
                      int K, int lda, int ldb, int ldc,
                      long long sA1, long long sA2, long long sB1, long long sB2,
                      long long sC1, long long sC2, int zm,
                      float alpha, int mode, int causal_skip, int causal_k,
                      int tri, int lptrev,
                      float* __restrict__ hhfp, const float* __restrict__ coefp,
                      u16* __restrict__ hbsp, u16* __restrict__ htsp,
                      const float* __restrict__ hp, u16* __restrict__ dbp)
{
    int bn, bm, bz;
    if (tri) {
        int Ntot = gridDim.x;
        int f = xcd_swizzle(blockIdx.x, Ntot);
        bz = f / tri;
        int r = f - bz * tri;
        bm = (int)((sqrtf(8.0f * (float)r + 1.0f) - 1.0f) * 0.5f);
        while ((bm + 1) * (bm + 2) / 2 <= r) bm++;
        while (bm * (bm + 1) / 2 > r) bm--;
        bn = r - bm * (bm + 1) / 2;
    } else {
        int gx = gridDim.x, gy = gridDim.y;
        int Ntot = gx * gy * gridDim.z;
        int gflat = xcd_swizzle(blockIdx.x + gx * (blockIdx.y + gy * blockIdx.z), Ntot);
        bn = gflat % gx;
        int rest = gflat / gx;
        bm = rest % gy;
        bz = rest / gy;
        if (lptrev) bm = gy - 1 - bm;      // heavy causal-K tiles first
        if (causal_skip && bn > bm) return;
    }
    int bz1 = bz % zm, bz2 = bz / zm;

    const u16* Ab = A + bz1 * sA1 + bz2 * sA2 + (long long)(bm * 64) * lda;
    const u16* Bb = B + bz1 * sB1 + bz2 * sB2 + (long long)(bn * 64) * ldb;

    __shared__ u16 sm[8 * 64 * 32];    // 32 KB: A0 B0 A1 B1 A2 B2 A3 B3
    const int PS = 64 * 32;            // panel stride (2048 u16)

    int tid  = threadIdx.x;
    int lane = tid & 63;
    int wave = tid >> 6;

    int k_end = causal_k ? min(K, (bm + 1) * 64) : K;

    f32x4 acc[4];
    #pragma unroll
    for (int j = 0; j < 4; j++) acc[j] = (f32x4){0.f, 0.f, 0.f, 0.f};

    int srow   = tid >> 2;             // 0..63
    int schunk = (tid & 3) * 8;
    int scq    = ((tid & 3) ^ slot_f(srow)) * 8;   // swizzled global chunk
    int fm     = lane & 15;
    int fk     = (lane >> 4) * 8;

    int k0 = 0;
    while (k0 < k_end) {
        __syncthreads();
        if (k_end - k0 >= 128) {
            #pragma unroll
            for (int p = 0; p < 4; p++) {
                long long ra  = (long long)srow * lda + k0 + p * 32 + scq;
                long long rb2 = (long long)srow * ldb + k0 + p * 32 + scq;
                GLD16(Ab + ra,  sm + (2 * p) * PS + srow * 32 + schunk);
                GLD16(Bb + rb2, sm + (2 * p + 1) * PS + srow * 32 + schunk);
            }
            __syncthreads();
            #pragma unroll
            for (int p = 0; p < 4; p++) {
                const u16* Al = sm + (2 * p) * PS;
                const u16* Bl = sm + (2 * p + 1) * PS;
                int Ra = wave * 16 + fm;
                bh8 af = *(const bh8*)(Al + Ra * 32 + (fk ^ (slot_f(Ra) * 8)));
                bh8 bf[4];
                #pragma unroll
                for (int j = 0; j < 4; j++) {
                    int Rb = j * 16 + fm;
                    bf[j] = *(const bh8*)(Bl + Rb * 32 + (fk ^ (slot_f(Rb) * 8)));
                }
                #pragma unroll
                for (int j = 0; j < 4; j++)
                    acc[j] = __builtin_amdgcn_mfma_f32_16x16x32_bf16(af, bf[j], acc[j], 0, 0, 0);
            }
            k0 += 128;
        } else {
            #pragma unroll
            for (int p = 0; p < 2; p++) {
                long long ra  = (long long)srow * lda + k0 + p * 32 + scq;
                long long rb2 = (long long)srow * ldb + k0 + p * 32 + scq;
                GLD16(Ab + ra,  sm + (2 * p) * PS + srow * 32 + schunk);
                GLD16(Bb + rb2, sm + (2 * p + 1) * PS + srow * 32 + schunk);
            }
            __syncthreads();
            #pragma unroll
            for (int p = 0; p < 2; p++) {
                const u16* Al = sm + (2 * p) * PS;
                const u16* Bl = sm + (2 * p + 1) * PS;
                int Ra = wave * 16 + fm;
                bh8 af = *(const bh8*)(Al + Ra * 32 + (fk ^ (slot_f(Ra) * 8)));
                bh8 bf[4];
                #pragma unroll
                for (int j = 0; j < 4; j++) {
                    int Rb = j * 16 + fm;
                    bf[j] = *(const bh8*)(Bl + Rb * 32 + (fk ^ (slot_f(Rb) * 8)));
                }
                #pragma unroll
                for (int j = 0; j < 4; j++)
                    acc[j] = __builtin_amdgcn_mfma_f32_16x16x32_bf16(af, bf[j], acc[j], 0, 0, 0);
            }
            k0 += 64;
        }
    }

    int rbase = bm * 64 + wave * 16 + (lane >> 4) * 4;
    int cbase = bn * 64 + (lane & 15);
    long long zoff = bz1 * sC1 + bz2 * sC2;
    if (mode == 1) {
        u16* C = (u16*)Cv + zoff;
        #pragma unroll
        for (int j = 0; j < 4; j++)
            #pragma unroll
            for (int r = 0; r < 4; r++)
                C[(long long)(rbase + r) * ldc + cbase + j * 16] = f2bf(acc[j][r] * alpha);
    } else if (mode == 3) {
        u16* C = (u16*)Cv + zoff;
        #pragma unroll
        for (int j = 0; j < 4; j++)
            #pragma unroll
            for (int r = 0; r < 4; r++) {
                union { _Float16 h; u16 u; } cv;
                cv.h = (_Float16)(acc[j][r] * alpha);
                C[(long long)(rbase + r) * ldc + cbase + j * 16] = cv.u;
            }
    } else if (mode == 5) {
        // par PV + delta: bz1 = batch b, bz2 = chamber ch
        int b = bz1, ch = bz2;
        #pragma unroll
        for (int r = 0; r < 4; r++) {
            int t = rbase + r;
            long long rowg = (long long)b * T_SEQ + t;
            float cf = coefp[(long long)ch * ROWS + rowg];
            #pragma unroll
            for (int j = 0; j < 4; j++) {
                int d = cbase + j * 16;
                float hv = hp[rowg * D_MODEL + d];
                dbp[rowg * KM + ch * D_MODEL + d] = f2bf(cf * (acc[j][r] - hv));
            }
        }
    } else if (mode == 6) {
        __syncthreads();               // staging LDS dead; reuse as transpose tile
        u16* tile = sm;                // [64][66] = 4224 u16, fits
        #pragma unroll
        for (int r = 0; r < 4; r++) {
            int t = rbase + r;
            long long rowg = (long long)bz1 * T_SEQ + t;
            float cf = coefp[rowg];
            int tl = t - bm * 64;
            #pragma unroll
            for (int j = 0; j < 4; j++) {
                int d = cbase + j * 16;
                long long idx = rowg * D_MODEL + d;
                float v = hhfp[idx];
                float nh = v + cf * (acc[j][r] - v);
                hhfp[idx] = nh;
                u16 w = f2bf(nh);
                hbsp[idx] = w;
                tile[((lane & 15) + j * 16) * 66 + tl] = w;
            }
        }
        __syncthreads();
        int dl = tid >> 2, tch = (tid & 3) * 16;
        long long ob = (long long)bz1 * T_SEQ * D_MODEL +
                       (long long)(bn * 64 + dl) * T_SEQ + bm * 64 + tch;
        #pragma unroll
        for (int kk = 0; kk < 16; kk++)
            htsp[ob + kk] = tile[dl * 66 + tch + kk];
    } else {
        float* C = (float*)Cv + zoff;
        #pragma unroll
        for (int j = 0; j < 4; j++)
            #pragma unroll
            for (int r = 0; r < 4; r++)
                C[(long long)(rbase + r) * ldc + cbase + j * 16] = acc[j][r] * alpha;
    }
}

// ---------------------------------------------------------------------------
// Shared 64x64 K-loop core for the fused seq chain (identical arithmetic to
// gemm64_nt_kernel's inner loop, incl. LDS slot swizzle).
// ---------------------------------------------------------------------------
__device__ __forceinline__ void g64_core(const u16* __restrict__ Ab,
                                         const u16* __restrict__ Bb,
                                         int lda, int ldb, int k_end,
                                         u16* sm, f32x4 acc[4],
                                         int tid, int lane, int wave)
{
    const int PS = 64 * 32;
    int srow   = tid >> 2;
    int schunk = (tid & 3) * 8;
    int scq    = ((tid & 3) ^ slot_f(srow)) * 8;
    int fm     = lane & 15;
    int fk     = (lane >> 4) * 8;

    int k0 = 0;
    while (k0 < k_end) {
        __syncthreads();
        if (k_end - k0 >= 128) {
            #pragma unroll
            for (int p = 0; p < 4; p++) {
                long long ra  = (long long)srow * lda + k0 + p * 32 + scq;
                long long rb2 = (long long)srow * ldb + k0 + p * 32 + scq;
                GLD16(Ab + ra,  sm + (2 * p) * PS + srow * 32 + schunk);
                GLD16(Bb + rb2, sm + (2 * p + 1) * PS + srow * 32 + schunk);
            }
            __syncthreads();
            #pragma unroll
            for (int p = 0; p < 4; p++) {
                const u16* Al = sm + (2 * p) * PS;
                const u16* Bl = sm + (2 * p + 1) * PS;
                int Ra = wave * 16 + fm;
                bh8 af = *(const bh8*)(Al + Ra * 32 + (fk ^ (slot_f(Ra) * 8)));
                bh8 bf[4];
                #pragma unroll
                for (int j = 0; j < 4; j++) {
                    int Rb = j * 16 + fm;
                    bf[j] = *(const bh8*)(Bl + Rb * 32 + (fk ^ (slot_f(Rb) * 8)));
                }
                #pragma unroll
                for (int j = 0; j < 4; j++)
                    acc[j] = __builtin_amdgcn_mfma_f32_16x16x32_bf16(af, bf[j], acc[j], 0, 0, 0);
            }
            k0 += 128;
        } else {
            #pragma unroll
            for (int p = 0; p < 2; p++) {
                long long ra  = (long long)srow * lda + k0 + p * 32 + scq;
                long long rb2 = (long long)srow * ldb + k0 + p * 32 + scq;
                GLD16(Ab + ra,  sm + (2 * p) * PS + srow * 32 + schunk);
                GLD16(Bb + rb2, sm + (2 * p + 1) * PS + srow * 32 + schunk);
            }
            __syncthreads();
            #pragma unroll
            for (int p = 0; p < 2; p++) {
                const u16* Al = sm + (2 * p) * PS;
                const u16* Bl = sm + (2 * p + 1) * PS;
                int Ra = wave * 16 + fm;
                bh8 af = *(const bh8*)(Al + Ra * 32 + (fk ^ (slot_f(Ra) * 8)));
                bh8 bf[4];
                #pragma unroll
                for (int j = 0; j < 4; j++) {
                    int Rb = j * 16 + fm;
                    bf[j] = *(const bh8*)(Bl + Rb * 32 + (fk ^ (slot_f(Rb) * 8)));
                }
                #pragma unroll
                for (int j = 0; j < 4; j++)
                    acc[j] = __builtin_amdgcn_mfma_f32_16x16x32_bf16(af, bf[j], acc[j], 0, 0, 0);
            }
            k0 += 64;
        }
    }
}

// ---------------------------------------------------------------------------
// causal softmax row, f16 in -> bf16 out, in place
// ---------------------------------------------------------------------------
__device__ __forceinline__ void softmax_row(u16* row, int len, int tid, int lane, int wave,
                                            float* red)
{
    float ev[4];
    float m = -3.0e38f;
    #pragma unroll
    for (int k = 0; k < 4; k++) {
        int s = tid + k * 256;
        if (s < len) {
            union { u16 u; _Float16 h; } cv; cv.u = row[s];
            ev[k] = (float)cv.h;
        } else ev[k] = -3.0e38f;
        m = fmaxf(m, ev[k]);
    }
    m = wred_max(m);
    if (lane == 0) red[wave] = m;
    __syncthreads();
    m = fmaxf(fmaxf(red[0], red[1]), fmaxf(red[2], red[3]));
    __syncthreads();
    float sum = 0.f;
    #pragma unroll
    for (int k = 0; k < 4; k++) {
        int s = tid + k * 256;
        float e = (s < len) ? __expf(ev[k] - m) : 0.f;
        ev[k] = e; sum += e;
    }
    sum = wred_sum(sum);
    if (lane == 0) red[wave] = sum;
    __syncthreads();
    sum = red[0] + red[1] + red[2] + red[3];
    float inv = 1.f / sum;
    #pragma unroll
    for (int k = 0; k < 4; k++)
        row[tid + k * 256] = f2bf(ev[k] * inv);
}

__global__ __launch_bounds__(256)
void softmax_kernel(u16* __restrict__ SP)
{
    int t = blockIdx.x, z = blockIdx.y;
    __shared__ float red[4];
    int tid = threadIdx.x, lane = tid & 63, wave = tid >> 6;
    softmax_row(SP + (long long)z * T_SEQ * T_SEQ + (long long)t * T_SEQ,
                t + 1, tid, lane, wave, red);
}

// ---------------------------------------------------------------------------
// FUSED seq chain: 7 chambers x {U, scores, softmax+coef, PV}, flag-array
// grid barrier between stages. NORMAL launch (graph-capture-safe) with
// guaranteed co-residency: 768 blocks = 3/CU x 256 CUs (passed R7, occ 37%).
// Stage bodies = round-5 dispatched kernels, bitwise-same arithmetic.
// ---------------------------------------------------------------------------
__global__ __launch_bounds__(256, 3)
void seq_chain_kernel(u16* __restrict__ hbs, const u16* __restrict__ Mtb,
                      u16* __restrict__ Useq, u16* __restrict__ Sseq,
                      float* __restrict__ hhf, u16* __restrict__ hts0,
                      u16* __restrict__ hts1, float* __restrict__ coefS,
                      const float* __restrict__ gw, const float* __restrict__ gb,
                      const float* __restrict__ sp,
                      unsigned* __restrict__ arrive, unsigned* __restrict__ go)
{
    __shared__ u16 sm[8 * 64 * 32];    // 32 KB, reused by every stage
    __shared__ float red[4];

    const long long DD  = (long long)D_MODEL * D_MODEL;
    const long long TD  = (long long)T_SEQ * D_MODEL;
    const long long TTs = (long long)T_SEQ * T_SEQ;
    const float sc = 1.0f / sqrtf((float)D_MODEL);

    int tid  = threadIdx.x;
    int lane = tid & 63;
    int wave = tid >> 6;
    int gen = 0;

    for (int ch = 0; ch < NCH; ch++) {
        const u16* Mt = Mtb + (long long)ch * DD;
        u16* htsCur = (ch & 1) ? hts1 : hts0;
        u16* htsNxt = (ch & 1) ? hts0 : hts1;

        // ---------- stage A: U = hbs @ Mt^T  (768 tiles: 12 bn x 64 bm) ----
        {
            int id = xcd_swizzle(blockIdx.x, 768);
            int bn = id % 12, bm = id / 12;
            f32x4 acc[4];
            #pragma unroll
            for (int j = 0; j < 4; j++) acc[j] = (f32x4){0.f, 0.f, 0.f, 0.f};
            g64_core(hbs + (long long)(bm * 64) * D_MODEL,
                     Mt  + (long long)(bn * 64) * D_MODEL,
                     D_MODEL, D_MODEL, D_MODEL, sm, acc, tid, lane, wave);
            int rbase = bm * 64 + wave * 16 + (lane >> 4) * 4;
            int cbase = bn * 64 + (lane & 15);
            #pragma unroll
            for (int j = 0; j < 4; j++)
                #pragma unroll
                for (int r = 0; r < 4; r++)
                    Useq[(long long)(rbase + r) * D_MODEL + cbase + j * 16] = f2bf(acc[j][r]);
        }
        grid_bar(arrive, go, ++gen);

        // ---------- stage B: scores = U @ hbs^T * sc (544 tri tiles) -------
        if (blockIdx.x < 544) {
            int f = xcd_swizzle(blockIdx.x, 544);
            int bz = f / 136;
            int r2 = f - bz * 136;
            int bm = (int)((sqrtf(8.0f * (float)r2 + 1.0f) - 1.0f) * 0.5f);
            while ((bm + 1) * (bm + 2) / 2 <= r2) bm++;
            while (bm * (bm + 1) / 2 > r2) bm--;
            int bn = r2 - bm * (bm + 1) / 2;
            f32x4 acc[4];
            #pragma unroll
            for (int j = 0; j < 4; j++) acc[j] = (f32x4){0.f, 0.f, 0.f, 0.f};
            g64_core(Useq + bz * TD + (long long)(bm * 64) * D_MODEL,
                     hbs  + bz * TD + (long long)(bn * 64) * D_MODEL,
                     D_MODEL, D_MODEL, D_MODEL, sm, acc, tid, lane, wave);
            u16* C = Sseq + bz * TTs;
            int rbase = bm * 64 + wave * 16 + (lane >> 4) * 4;
            int cbase = bn * 64 + (lane & 15);
            #pragma unroll
            for (int j = 0; j < 4; j++)
                #pragma unroll
                for (int r = 0; r < 4; r++) {
                    union { _Float16 h; u16 u; } cv;
                    cv.h = (_Float16)(acc[j][r] * sc);
                    C[(long long)(rbase + r) * T_SEQ + cbase + j * 16] = cv.u;
                }
        }
        grid_bar(arrive, go, ++gen);

        // ---------- stage C: softmax rows (z<4) + gate coef (z==4) ---------
        for (int u = blockIdx.x; u < 5 * T_SEQ; u += 768) {
            __syncthreads();                       // protect red[] reuse
            int t = u & (T_SEQ - 1), z = u >> 10;
            if (z == BATCH) {
                int row = t * 4 + wave;
                long long base = (long long)row * D_MODEL;
                const float* g = gw + ch * D_MODEL;
                float dot = 0.f;
                #pragma unroll
                for (int k = 0; k < 12; k++) dot += hhf[base + lane + 64 * k] * g[lane + 64 * k];
                dot = wred_sum(dot);
                if (lane == 0) {
                    float gate = 1.f / (1.f + __expf(-(dot + gb[ch])));
                    coefS[row] = log1pf(expf(sp[ch])) * chamber_mask(ch) * gate;
                }
            } else {
                softmax_row(Sseq + (long long)z * TTs + (long long)t * T_SEQ,
                            t + 1, tid, lane, wave, red);
            }
        }
        grid_bar(arrive, go, ++gen);

        // ---------- stage D: PV + delta (768 tiles: 12 bn x 16 bm x 4 b) ---
        {
            int id = xcd_swizzle(blockIdx.x, 768);
            int bn = id % 12;
            int rest = id / 12;
            int bm = rest % 16;
            int bz = rest / 16;
            bm = 15 - bm;                          // LPT heavy-first
            int k_end = (bm + 1) * 64;             // causal-K
            f32x4 acc[4];
            #pragma unroll
            for (int j = 0; j < 4; j++) acc[j] = (f32x4){0.f, 0.f, 0.f, 0.f};
            g64_core(Sseq   + bz * TTs + (long long)(bm * 64) * T_SEQ,
                     htsCur + bz * TD  + (long long)(bn * 64) * T_SEQ,
                     T_SEQ, T_SEQ, k_end, sm, acc, tid, lane, wave);

            int rbase = bm * 64 + wave * 16 + (lane >> 4) * 4;
            int cbase = bn * 64 + (lane & 15);
            __syncthreads();                       // staging LDS dead; reuse
            u16* tile = sm;                        // [64][66]
            #pragma unroll
            for (int r = 0; r < 4; r++) {
                int t = rbase + r;
                long long rowg = (long long)bz * T_SEQ + t;
                float cf = coefS[rowg];
                int tl = t - bm * 64;
                #pragma unroll
                for (int j = 0; j < 4; j++) {
                    int d = cbase + j * 16;
                    long long idx = rowg * D_MODEL + d;
                    float v = hhf[idx];
                    float nh = v + cf * (acc[j][r] - v);
                    hhf[idx] = nh;
                    u16 w = f2bf(nh);
                    hbs[idx] = w;
                    tile[((lane & 15) + j * 16) * 66 + tl] = w;
                }
            }
            __syncthreads();
            int dl = tid >> 2, tch = (tid & 3) * 16;
            long long ob = (long long)bz * TD +
                           (long long)(bn * 64 + dl) * T_SEQ + bm * 64 + tch;
            #pragma unroll
            for (int kk = 0; kk < 16; kk++)
                htsNxt[ob + kk] = tile[dl * 66 + tch + kk];
        }
        if (ch != NCH - 1) grid_bar(arrive, go, ++gen);   // kernel exit orders the last
    }
}

// ---------------------------------------------------------------------------
// LN pre: h = LN(x)*g+b; hhf = h; hbp = hbs = bf16(h)
// ---------------------------------------------------------------------------
__global__ __launch_bounds__(256)
void ln_pre_kernel(const float* __restrict__ x, const float* __restrict__ g,
                   const float* __restrict__ b, float* __restrict__ h,
                   float* __restrict__ hhf, u16* __restrict__ hbp,
                   u16* __restrict__ hbs)
{
    int row = blockIdx.x;
    long long base = (long long)row * D_MODEL;
    int tid = threadIdx.x, lane = tid & 63, wave = tid >> 6;
    __shared__ float red[4];
    float v[3]; float s = 0.f;
    #pragma unroll
    for (int k = 0; k < 3; k++) { v[k] = x[base + tid + k * 256]; s += v[k]; }
    s = wred_sum(s);
    if (lane == 0) red[wave] = s;
    __syncthreads();
    float mean = (red[0] + red[1] + red[2] + red[3]) * (1.f / D_MODEL);
    __syncthreads();
    float sq = 0.f;
    #pragma unroll
    for (int k = 0; k < 3; k++) { float dd = v[k] - mean; sq += dd * dd; }
    sq = wred_sum(sq);
    if (lane == 0) red[wave] = sq;
    __syncthreads();
    float var = (red[0] + red[1] + red[2] + red[3]) * (1.f / D_MODEL);
    float rstd = rsqrtf(var + 1e-5f);
    #pragma unroll
    for (int k = 0; k < 3; k++) {
        int c = tid + k * 256;
        float o = (v[k] - mean) * rstd * g[c] + b[c];
        h[base + c] = o; hhf[base + c] = o;
        u16 w = f2bf(o);
        hbp[base + c] = w; hbs[base + c] = w;
    }
}

// ---------------------------------------------------------------------------
// bf16 transpose, dual output
// ---------------------------------------------------------------------------
__global__ __launch_bounds__(256)
void transpose2_kernel(const u16* __restrict__ hb, u16* __restrict__ htp,
                       u16* __restrict__ hts)
{
    __shared__ u16 tile[32][33];
    int b = blockIdx.z;
    int d0 = blockIdx.x * 32, t0 = blockIdx.y * 32;
    int tx = threadIdx.x & 31, ty = threadIdx.x >> 5;
    long long bb = (long long)b * T_SEQ * D_MODEL;
    #pragma unroll
    for (int i = 0; i < 32; i += 8)
        tile[ty + i][tx] = hb[bb + (long long)(t0 + ty + i) * D_MODEL + d0 + tx];
    __syncthreads();
    #pragma unroll
    for (int i = 0; i < 32; i += 8) {
        long long o = bb + (long long)(d0 + ty + i) * T_SEQ + t0 + tx;
        u16 w = tile[tx][ty + i];
        htp[o] = w; hts[o] = w;
    }
}

// ---------------------------------------------------------------------------
// par coef: gate coefficient per row for all 7 chambers (frozen h)
// ---------------------------------------------------------------------------
__global__ __launch_bounds__(256)
void coef_par_kernel(const float* __restrict__ h, const float* __restrict__ gw,
                     const float* __restrict__ gb, const float* __restrict__ sp,
                     float* __restrict__ coefP)
{
    int row = blockIdx.x * 4 + (threadIdx.x >> 6);
    int lane = threadIdx.x & 63;
    long long base = (long long)row * D_MODEL;
    float hv[12];
    #pragma unroll
    for (int k = 0; k < 12; k++) hv[k] = h[base + lane + 64 * k];
    for (int ci = 0; ci < NCH; ci++) {
        const float* g = gw + ci * D_MODEL;
        float dot = 0.f;
        #pragma unroll
        for (int k = 0; k < 12; k++) dot += hv[k] * g[lane + 64 * k];
        dot = wred_sum(dot);
        if (lane == 0) {
            float gate = 1.f / (1.f + __expf(-(dot + gb[ci])));
            coefP[ci * ROWS + row] = log1pf(expf(sp[ci])) * chamber_mask(ci) * gate;
        }
    }
}

// ---------------------------------------------------------------------------
__global__ __launch_bounds__(256)
void cast4_kernel(const float4* __restrict__ in, ushort4* __restrict__ outp, int n4)
{
    int i = blockIdx.x * 256 + threadIdx.x;
    if (i < n4) {
        float4 v = in[i];
        ushort4 o;
        o.x = f2bf(v.x); o.y = f2bf(v.y); o.z = f2bf(v.z); o.w = f2bf(v.w);
        outp[i] = o;
    }
}

// ---------------------------------------------------------------------------
// final: par = sum of 7 bf16 partial slabs; e = (1-mg)*(hhf-h) + mg*par;
// out = x + rg*(LN(e)*g+b)
// ---------------------------------------------------------------------------
__global__ __launch_bounds__(256)
void final_kernel(const float* __restrict__ x, const float* __restrict__ h,
                  const float* __restrict__ hhf, const u16* __restrict__ Pp,
                  const float* __restrict__ mode_logit, const float* __restrict__ residual_gate,
                  const float* __restrict__ g, const float* __restrict__ b,
                  float* __restrict__ out)
{
    const long long RDe = (long long)ROWS * D_MODEL;
    int row = blockIdx.x;
    long long base = (long long)row * D_MODEL;
    int tid = threadIdx.x, lane = tid & 63, wave = tid >> 6;
    __shared__ float red[4];
    float mg = 1.f / (1.f + __expf(-mode_logit[0]));
    float rg = residual_gate[0];
    float e[3]; float s = 0.f;
    #pragma unroll
    for (int k = 0; k < 3; k++) {
        int c = tid + k * 256;
        float p = 0.f;
        #pragma unroll
        for (int z = 0; z < NCH; z++) p += bf2f(Pp[z * RDe + base + c]);
        float v = (1.f - mg) * (hhf[base + c] - h[base + c]) + mg * p;
        e[k] = v; s += v;
    }
    s = wred_sum(s);
    if (lane == 0) red[wave] = s;
    __syncthreads();
    float mean = (red[0] + red[1] + red[2] + red[3]) * (1.f / D_MODEL);
    __syncthreads();
    float sq = 0.f;
    #pragma unroll
    for (int k = 0; k < 3; k++) { float dd = e[k] - mean; sq += dd * dd; }
    sq = wred_sum(sq);
    if (lane == 0) red[wave] = sq;
    __syncthreads();
    float var = (red[0] + red[1] + red[2] + red[3]) * (1.f / D_MODEL);
    float rstd = rsqrtf(var + 1e-5f);
    #pragma unroll
    for (int k = 0; k < 3; k++) {
        int c = tid + k * 256;
        out[base + c] = x[base + c] + rg * ((e[k] - mean) * rstd * g[c] + b[c]);
    }
}

// ---------------------------------------------------------------------------
extern "C" void kernel_launch(void* const* d_in, const int* in_sizes, int n_in,
                              void* d_out, int out_size, void* d_ws, size_t ws_size,
                              hipStream_t stream)
{
    (void)in_sizes; (void)n_in; (void)out_size; (void)ws_size;
    const float* x             = (const float*)d_in[0];
    const float* Wq            = (const float*)d_in[1];
    const float* Wk            = (const float*)d_in[2];
    const float* gate_w        = (const float*)d_in[3];
    const float* gate_b        = (const float*)d_in[4];
    const float* scale_p       = (const float*)d_in[5];
    const float* merge_W       = (const float*)d_in[6];
    const float* mode_logit    = (const float*)d_in[7];
    const float* residual_gate = (const float*)d_in[8];
    const float* ln_pre_g      = (const float*)d_in[9];
    const float* ln_pre_b      = (const float*)d_in[10];
    const float* ln_post_g     = (const float*)d_in[11];
    const float* ln_post_b     = (const float*)d_in[12];
    float* out = (float*)d_out;

    const long long DD  = (long long)D_MODEL * D_MODEL;   // 589824
    const long long TD  = (long long)T_SEQ * D_MODEL;     // 786432
    const long long TTs = (long long)T_SEQ * T_SEQ;       // 1048576
    const long long RDe = (long long)ROWS * D_MODEL;      // 3145728
    const int NTRI = 16 * 17 / 2;                         // 136 live causal tiles
    const size_t BARBYTES = (size_t)(SEQ_NBLK + NGO) * BAR_STRIDE * 4;  // ~100KB

    size_t off = 0;
    char* wsb = (char*)d_ws;
    auto alloc = [&](size_t bytes) -> void* {
        void* p = wsb + off; off += (bytes + 255) & ~(size_t)255; return p;
    };
    u16*   Mtb  = (u16*)alloc((size_t)NCH * DD * 2);
    u16*   mgb  = (u16*)alloc((size_t)D_MODEL * KM * 2);
    float* h    = (float*)alloc(RDe * 4);
    float* hhf  = (float*)alloc(RDe * 4);
    u16*   hbp  = (u16*)alloc(RDe * 2);
    u16*   htp  = (u16*)alloc(RDe * 2);
    u16*   hbs  = (u16*)alloc(RDe * 2);
    u16*   hts0 = (u16*)alloc(RDe * 2);
    u16*   hts1 = (u16*)alloc(RDe * 2);
    u16*   Spar = (u16*)alloc((size_t)(NCH * BATCH) * TTs * 2);
    u16*   Sseq = (u16*)alloc((size_t)BATCH * TTs * 2);
    u16*   Upar = (u16*)alloc((size_t)NCH * RDe * 2);
    u16*   Useq = (u16*)alloc(RDe * 2);
    u16*   db   = (u16*)alloc((size_t)ROWS * KM * 2);
    float* coefP= (float*)alloc((size_t)NCH * ROWS * 4);
    float* coefS= (float*)alloc((size_t)ROWS * 4);
    unsigned* barmem = (unsigned*)alloc(BARBYTES);
    unsigned* arrive = barmem;
    unsigned* go     = barmem + (size_t)SEQ_NBLK * BAR_STRIDE;
    // transient aliases (stream-ordered lifetimes):
    u16*   Wqb  = Spar;                 // dead before Spar written
    u16*   Wkb  = Spar + (size_t)NCH * DD;
    u16*   Pp   = Upar;                 // merge partials: Upar dead after par scores

    const float sc = 1.0f / sqrtf((float)D_MODEL);
    const int N4W = (int)((size_t)NCH * DD) / 4;
    const int N4M = (int)((size_t)D_MODEL * KM) / 4;

    hipMemsetAsync(barmem, 0, BARBYTES, stream);  // reset barrier flags every replay

    ln_pre_kernel<<<ROWS, 256, 0, stream>>>(x, ln_pre_g, ln_pre_b, h, hhf, hbp, hbs);
    cast4_kernel<<<(N4W + 255) / 256, 256, 0, stream>>>((const float4*)Wq, (ushort4*)Wqb, N4W);
    cast4_kernel<<<(N4W + 255) / 256, 256, 0, stream>>>((const float4*)Wk, (ushort4*)Wkb, N4W);
    cast4_kernel<<<(N4M + 255) / 256, 256, 0, stream>>>((const float4*)merge_W, (ushort4*)mgb, N4M);
    transpose2_kernel<<<dim3(24, 32, BATCH), 256, 0, stream>>>(hbp, htp, hts0);
    coef_par_kernel<<<ROWS / 4, 256, 0, stream>>>(h, gate_w, gate_b, scale_p, coefP);

    // Mt_i[d'][d] = sum_e Wk_i[d'][e] Wq_i[d][e]
    gemm_nt_kernel<<<dim3(6, 6, NCH), 256, 0, stream>>>(
        Wkb, Wqb, Mtb, D_MODEL, D_MODEL, D_MODEL, D_MODEL,
        DD, 0, DD, 0, DD, 0, NCH, 1.f, 1, 0, 0, 0, 0);

    // ======================= par branch (frozen h, batched over chambers) ====
    // U_i = hbp @ Mt_i^T  (128-tile, 1344 blocks, swizzled)
    gemm_nt_kernel<<<dim3(6, 32, NCH), 256, 0, stream>>>(
        hbp, Mtb, Upar, D_MODEL, D_MODEL, D_MODEL, D_MODEL,
        0, 0, DD, 0, RDe, 0, NCH, 1.f, 1, 0, 0, 0, 0);
    // scores (64-tile, COMPACT: 136 live tiles x 28 z = 3808 blocks)
    gemm64_nt_kernel<<<dim3(NTRI * BATCH * NCH), 256, 0, stream>>>(
        Upar, hbp, Spar, D_MODEL, D_MODEL, D_MODEL, T_SEQ,
        TD, RDe, TD, 0, TTs, 4 * TTs, BATCH, sc, 3, 0, 0, NTRI, 0,
        nullptr, nullptr, nullptr, nullptr, nullptr, nullptr);
    softmax_kernel<<<dim3(T_SEQ, BATCH * NCH), 256, 0, stream>>>(Spar);
    // PV + delta (64-tile mode 5, LPT heavy-first): db = bf16(coef*(E - h))
    gemm64_nt_kernel<<<dim3(12, 16, BATCH * NCH), 256, 0, stream>>>(
        Spar, htp, nullptr, T_SEQ, T_SEQ, T_SEQ, D_MODEL,
        TTs, 4 * TTs, TD, 0, 0, 0, BATCH, 1.f, 5, 0, 1, 0, 1,
        nullptr, coefP, nullptr, nullptr, h, db);
    // merge partials: Pp[ch] = d_ch @ Wm_ch^T  (K-slice per z; Pp aliases Upar)
    gemm_nt_kernel<<<dim3(6, 32, NCH), 256, 0, stream>>>(
        db, mgb, Pp, KM, KM, KM, D_MODEL,
        0, 0, 0, 0, RDe, 0, NCH, 1.f, 1, 0, 0, D_MODEL, D_MODEL);

    // ======================= seq branch: ONE fused kernel ====================
    seq_chain_kernel<<<dim3(SEQ_NBLK), dim3(256), 0, stream>>>(
        hbs, Mtb, Useq, Sseq, hhf, hts0, hts1, coefS,
        gate_w, gate_b, scale_p, arrive, go);

    final_kernel<<<ROWS, 256, 0, stream>>>(x, h, hhf, Pp, mode_logit, residual_gate,
                                           ln_post_g, ln_post_b, out);
}

// Round 9
// 867.350 us; speedup vs baseline: 6.5225x; 6.5225x over previous
//
#include <hip/hip_runtime.h>
#include <math.h>

#define D_MODEL 768
#define T_SEQ   1024
#define BATCH   4
#define NCH     7
#define ROWS    4096            // BATCH*T_SEQ
#define KM      (NCH * D_MODEL) // 5376

typedef unsigned short u16;
typedef __attribute__((ext_vector_type(8))) short bh8;   // 8 x bf16
typedef __attribute__((ext_vector_type(4))) float f32x4;

__device__ __forceinline__ u16 f2bf(float f) {
    union { float f; unsigned u; } v; v.f = f;
    return (u16)((v.u + 0x7fffu + ((v.u >> 16) & 1u)) >> 16);  // RNE
}
__device__ __forceinline__ float bf2f(u16 b) {
    union { unsigned u; float f; } v; v.u = ((unsigned)b) << 16;
    return v.f;
}
__device__ __forceinline__ float wred_sum(float v) {
    #pragma unroll
    for (int o = 32; o; o >>= 1) v += __shfl_down(v, o, 64);
    return v;
}
__device__ __forceinline__ float chamber_mask(int i) {
    float slope = 8.0f * 7.0f / 2000.0f;
    return 1.0f / (1.0f + __expf(-slope * (4000.0f - 2000.0f * (i + 0.5f) / 7.0f)));
}

#define GLD16(g, l) __builtin_amdgcn_global_load_lds( \
    (const __attribute__((address_space(1))) void*)(g), \
    (__attribute__((address_space(3))) void*)(l), 16, 0, 0)

// XCD-aware swizzle (identity when N not divisible by 8).
__device__ __forceinline__ int xcd_swizzle(int gflat, int Ntot) {
    if ((Ntot & 7) == 0) {
        int chunk = Ntot >> 3;
        gflat = (gflat & 7) * chunk + (gflat >> 3);
    }
    return gflat;
}

// LDS slot swizzle — gemm64 ONLY (A/B: helps LDS-read-bound gemm64, hurts
// stage-bound gemm128 by ~10%). R7/R8 lesson (banked): in-kernel grid sync
// costs 130-190us/barrier on MI355X (per-block agent fences force per-XCD L2
// writeback/invalidate) — fused-chain with barriers is structurally dead.
__device__ __forceinline__ int slot_f(int row) { return (row >> 1) & 3; }

// ---------------------------------------------------------------------------
// 128x128-tile NT GEMM: C = alpha * A[M,K] * B[N,K]^T  (bf16 in)
// K=64 per barrier as TWO independent BK=32 panels; XCD tile swizzle.
// mode: 0 f32 store, 1 bf16 store, 3 f16 store
// kss/klen: K slice per bz1 (merge partials). All K extents multiple of 64.
// ---------------------------------------------------------------------------
__global__ __launch_bounds__(256)
void gemm_nt_kernel(const u16* __restrict__ A, const u16* __restrict__ B,
                    void* __restrict__ Cv,
                    int K, int lda, int ldb, int ldc,
                    long long sA1, long long sA2, long long sB1, long long sB2,
                    long long sC1, long long sC2, int zm,
                    float alpha, int mode, int causal_skip, int causal_k,
                    int kss, int klen)
{
    int gx = gridDim.x, gy = gridDim.y;
    int Ntot = gx * gy * gridDim.z;
    int gflat = xcd_swizzle(blockIdx.x + gx * (blockIdx.y + gy * blockIdx.z), Ntot);
    int bn = gflat % gx;
    int rest = gflat / gx;
    int bm = rest % gy;
    int bz = rest / gy;
    if (causal_skip && bn > bm) return;
    int bz1 = bz % zm, bz2 = bz / zm;

    const u16* Ab = A + bz1 * sA1 + bz2 * sA2 + (long long)(bm * 128) * lda;
    const u16* Bb = B + bz1 * sB1 + bz2 * sB2 + (long long)(bn * 128) * ldb;

    __shared__ u16 sm[4 * 128 * 32];   // 32 KB: A0|B0|A1|B1 panels
    u16* Al0 = sm;
    u16* Bl0 = sm + 128 * 32;
    u16* Al1 = sm + 2 * 128 * 32;
    u16* Bl1 = sm + 3 * 128 * 32;

    int tid  = threadIdx.x;
    int lane = tid & 63;
    int wave = tid >> 6;
    int wm = wave >> 1, wn = wave & 1;

    int k_begin = kss ? bz1 * kss : 0;
    int k_end   = klen ? (k_begin + klen) : K;
    if (causal_k) k_end = min(k_end, (bm + 1) * 128);

    f32x4 acc[4][4];
    #pragma unroll
    for (int i = 0; i < 4; i++)
        #pragma unroll
        for (int j = 0; j < 4; j++)
            acc[i][j] = (f32x4){0.f, 0.f, 0.f, 0.f};

    int srow = lane >> 2;
    int skq  = (lane & 3) * 8;
    int fm   = lane & 15;
    int fk   = (lane >> 4) * 8;

    for (int k0 = k_begin; k0 < k_end; k0 += 64) {
        __syncthreads();
        #pragma unroll
        for (int r = 0; r < 2; r++) {
            int row = r * 64 + wave * 16 + srow;
            long long ra = (long long)row * lda + k0 + skq;
            long long rb2 = (long long)row * ldb + k0 + skq;
            GLD16(Ab + ra,       Al0 + row * 32 + skq);
            GLD16(Bb + rb2,      Bl0 + row * 32 + skq);
            GLD16(Ab + ra + 32,  Al1 + row * 32 + skq);
            GLD16(Bb + rb2 + 32, Bl1 + row * 32 + skq);
        }
        __syncthreads();

        #pragma unroll
        for (int p = 0; p < 2; p++) {
            const u16* Al = p ? Al1 : Al0;
            const u16* Bl = p ? Bl1 : Bl0;
            bh8 af[4], bf[4];
            #pragma unroll
            for (int i = 0; i < 4; i++)
                af[i] = *(const bh8*)(Al + (wm * 64 + i * 16 + fm) * 32 + fk);
            #pragma unroll
            for (int j = 0; j < 4; j++)
                bf[j] = *(const bh8*)(Bl + (wn * 64 + j * 16 + fm) * 32 + fk);
            #pragma unroll
            for (int i = 0; i < 4; i++)
                #pragma unroll
                for (int j = 0; j < 4; j++)
                    acc[i][j] = __builtin_amdgcn_mfma_f32_16x16x32_bf16(af[i], bf[j], acc[i][j], 0, 0, 0);
        }
    }

    int rbase = bm * 128 + wm * 64 + (lane >> 4) * 4;
    int cbase = bn * 128 + wn * 64 + (lane & 15);
    long long zoff = bz1 * sC1 + bz2 * sC2;
    if (mode == 1) {
        u16* C = (u16*)Cv + zoff;
        #pragma unroll
        for (int i = 0; i < 4; i++)
            #pragma unroll
            for (int j = 0; j < 4; j++)
                #pragma unroll
                for (int r = 0; r < 4; r++)
                    C[(long long)(rbase + i * 16 + r) * ldc + cbase + j * 16] = f2bf(acc[i][j][r] * alpha);
    } else if (mode == 3) {
        u16* C = (u16*)Cv + zoff;
        #pragma unroll
        for (int i = 0; i < 4; i++)
            #pragma unroll
            for (int j = 0; j < 4; j++)
                #pragma unroll
                for (int r = 0; r < 4; r++) {
                    union { _Float16 h; u16 u; } cv;
                    cv.h = (_Float16)(acc[i][j][r] * alpha);
                    C[(long long)(rbase + i * 16 + r) * ldc + cbase + j * 16] = cv.u;
                }
    } else {
        float* C = (float*)Cv + zoff;
        #pragma unroll
        for (int i = 0; i < 4; i++)
            #pragma unroll
            for (int j = 0; j < 4; j++)
                #pragma unroll
                for (int r = 0; r < 4; r++)
                    C[(long long)(rbase + i * 16 + r) * ldc + cbase + j * 16] = acc[i][j][r] * alpha;
    }
}

// ---------------------------------------------------------------------------
// 64x64-tile NT GEMM — XCD tile swizzle + LDS slot swizzle.
// tri: compact triangular launch; ntri_blk>0: blocks with swizzled id >=
//   ntri_blk run the gate-coef body instead (params repurposed, see launch).
// lptrev: non-tri = LPT heavy-first; tri = chamber index ci for coef ext.
// mode: 0 f32, 1 bf16, 3 f16 (generic K-loop, K=128/barrier, 64 tail),
//       5 par PV+delta, 6 seq PV+delta — FUSED ONLINE SOFTMAX: A = raw f16
//       scaled scores; per 64-k tile compute row max (shfl_xor over fk-lanes),
//       rescale acc, exp->bf16->MFMA; normalize by running sum at end.
//       Replaces the softmax dispatch + P round-trip entirely.
// ---------------------------------------------------------------------------
__global__ __launch_bounds__(256)
void gemm64_nt_kernel(const u16* __restrict__ A, const u16* __restrict__ B,
                      void* __restrict__ Cv,
                      int K, int lda, int ldb, int ldc,
                      long long sA1, long long sA2, long long sB1, long long sB2,
                      long long sC1, long long sC2, int zm,
                      float alpha, int mode, int causal_skip, int causal_k,
                      int tri, int lptrev, int ntri_blk,
                      float* __restrict__ hhfp, const float* __restrict__ coefp,
                      u16* __restrict__ hbsp, u16* __restrict__ htsp,
                      const float* __restrict__ hp, u16* __restrict__ dbp)
{
    int tid  = threadIdx.x;
    int lane = tid & 63;
    int wave = tid >> 6;

    int bn, bm, bz;
    if (tri) {
        int Ntot = gridDim.x;
        int f = xcd_swizzle(blockIdx.x, Ntot);
        if (ntri_blk && f >= ntri_blk) {
            // gate-coef extension: 4 rows per block (one per wave).
            // param map: hhfp=coefS(out), coefp=hhf, hbsp=gw, htsp=gb, hp=sp,
            // lptrev=ci.
            int rowg = (f - ntri_blk) * 4 + wave;
            long long base = (long long)rowg * D_MODEL;
            const float* gwp = (const float*)hbsp;
            const float* gbp = (const float*)htsp;
            int ci = lptrev;
            float dot = 0.f;
            #pragma unroll
            for (int k = 0; k < 12; k++)
                dot += coefp[base + lane + 64 * k] * gwp[ci * D_MODEL + lane + 64 * k];
            dot = wred_sum(dot);
            if (lane == 0) {
                float gate = 1.f / (1.f + __expf(-(dot + gbp[ci])));
                hhfp[rowg] = log1pf(expf(hp[ci])) * chamber_mask(ci) * gate;
            }
            return;
        }
        bz = f / tri;
        int r = f - bz * tri;
        bm = (int)((sqrtf(8.0f * (float)r + 1.0f) - 1.0f) * 0.5f);
        while ((bm + 1) * (bm + 2) / 2 <= r) bm++;
        while (bm * (bm + 1) / 2 > r) bm--;
        bn = r - bm * (bm + 1) / 2;
    } else {
        int gx = gridDim.x, gy = gridDim.y;
        int Ntot = gx * gy * gridDim.z;
        int gflat = xcd_swizzle(blockIdx.x + gx * (blockIdx.y + gy * blockIdx.z), Ntot);
        bn = gflat % gx;
        int rest = gflat / gx;
        bm = rest % gy;
        bz = rest / gy;
        if (lptrev) bm = gy - 1 - bm;      // heavy causal-K tiles first
        if (causal_skip && bn > bm) return;
    }
    int bz1 = bz % zm, bz2 = bz / zm;

    const u16* Ab = A + bz1 * sA1 + bz2 * sA2 + (long long)(bm * 64) * lda;
    const u16* Bb = B + bz1 * sB1 + bz2 * sB2 + (long long)(bn * 64) * ldb;

    __shared__ u16 sm[8 * 64 * 32];    // 32 KB: A0 B0 A1 B1 A2 B2 A3 B3
    const int PS = 64 * 32;            // panel stride (2048 u16)

    int k_end = causal_k ? min(K, (bm + 1) * 64) : K;

    f32x4 acc[4];
    #pragma unroll
    for (int j = 0; j < 4; j++) acc[j] = (f32x4){0.f, 0.f, 0.f, 0.f};

    int srow   = tid >> 2;             // 0..63
    int schunk = (tid & 3) * 8;
    int scq    = ((tid & 3) ^ slot_f(srow)) * 8;   // swizzled global chunk
    int fm     = lane & 15;
    int fk     = (lane >> 4) * 8;

    if (mode == 5 || mode == 6) {
        // ---- fused online-softmax PV: A holds raw f16 scores (alpha'd) ----
        float m_run = -3.0e38f, s_run = 0.f;
        int row_l = wave * 16 + fm;            // local row of this lane's A-frag
        int nkt = k_end >> 6;
        for (int kt = 0; kt < nkt; kt++) {
            int k0b = kt << 6;
            __syncthreads();
            #pragma unroll
            for (int p = 0; p < 2; p++) {
                long long ra  = (long long)srow * lda + k0b + p * 32 + scq;
                long long rb2 = (long long)srow * ldb + k0b + p * 32 + scq;
                GLD16(Ab + ra,  sm + (2 * p) * PS + srow * 32 + schunk);
                GLD16(Bb + rb2, sm + (2 * p + 1) * PS + srow * 32 + schunk);
            }
            __syncthreads();
            int aoff = fk ^ (slot_f(row_l) * 8);
            bh8 a0 = *(const bh8*)(sm + 0 * PS + row_l * 32 + aoff);
            bh8 a1 = *(const bh8*)(sm + 2 * PS + row_l * 32 + aoff);
            float v[16];
            #pragma unroll
            for (int e = 0; e < 8; e++) {
                union { u16 u; _Float16 h; } c0, c1;
                c0.u = (u16)a0[e]; c1.u = (u16)a1[e];
                v[e] = (float)c0.h; v[8 + e] = (float)c1.h;
            }
            if (kt == nkt - 1) {               // diagonal tile: mask col > row
                #pragma unroll
                for (int e = 0; e < 8; e++) {
                    if (fk + e > row_l)      v[e]     = -3.0e38f;
                    if (32 + fk + e > row_l) v[8 + e] = -3.0e38f;
                }
            }
            float tmax = v[0];
            #pragma unroll
            for (int e = 1; e < 16; e++) tmax = fmaxf(tmax, v[e]);
            tmax = fmaxf(tmax, __shfl_xor(tmax, 16, 64));
            tmax = fmaxf(tmax, __shfl_xor(tmax, 32, 64));
            float m_new = fmaxf(m_run, tmax);
            float scale = __expf(m_run - m_new);   // 0 on first tile (underflow)
            float psum = 0.f;
            u16 pb[16];
            #pragma unroll
            for (int e = 0; e < 16; e++) {
                float pe = __expf(v[e] - m_new);
                psum += pe;
                pb[e] = f2bf(pe);
            }
            psum += __shfl_xor(psum, 16, 64);
            psum += __shfl_xor(psum, 32, 64);
            s_run = s_run * scale + psum;
            m_run = m_new;
            float fr[4];
            #pragma unroll
            for (int r = 0; r < 4; r++)
                fr[r] = __shfl(scale, ((lane >> 4) << 2) + r, 64);
            #pragma unroll
            for (int j = 0; j < 4; j++)
                #pragma unroll
                for (int r = 0; r < 4; r++)
                    acc[j][r] *= fr[r];
            bh8 pa0, pa1;
            #pragma unroll
            for (int e = 0; e < 8; e++) { pa0[e] = (short)pb[e]; pa1[e] = (short)pb[8 + e]; }
            #pragma unroll
            for (int p = 0; p < 2; p++) {
                const u16* Bl = sm + (2 * p + 1) * PS;
                bh8 pa = p ? pa1 : pa0;
                bh8 bf[4];
                #pragma unroll
                for (int j = 0; j < 4; j++) {
                    int Rb = j * 16 + fm;
                    bf[j] = *(const bh8*)(Bl + Rb * 32 + (fk ^ (slot_f(Rb) * 8)));
                }
                #pragma unroll
                for (int j = 0; j < 4; j++)
                    acc[j] = __builtin_amdgcn_mfma_f32_16x16x32_bf16(pa, bf[j], acc[j], 0, 0, 0);
            }
        }
        // normalize rows by running sum (>=1 always: diagonal col present)
        float invs[4];
        #pragma unroll
        for (int r = 0; r < 4; r++)
            invs[r] = 1.f / __shfl(s_run, ((lane >> 4) << 2) + r, 64);
        #pragma unroll
        for (int j = 0; j < 4; j++)
            #pragma unroll
            for (int r = 0; r < 4; r++)
                acc[j][r] *= invs[r];
    } else {
        // ---- generic K-loop (modes 0/1/3): 128/barrier, 64 tail ----
        int k0 = 0;
        while (k0 < k_end) {
            __syncthreads();
            if (k_end - k0 >= 128) {
                #pragma unroll
                for (int p = 0; p < 4; p++) {
                    long long ra  = (long long)srow * lda + k0 + p * 32 + scq;
                    long long rb2 = (long long)srow * ldb + k0 + p * 32 + scq;
                    GLD16(Ab + ra,  sm + (2 * p) * PS + srow * 32 + schunk);
                    GLD16(Bb + rb2, sm + (2 * p + 1) * PS + srow * 32 + schunk);
                }
                __syncthreads();
                #pragma unroll
                for (int p = 0; p < 4; p++) {
                    const u16* Al = sm + (2 * p) * PS;
                    const u16* Bl = sm + (2 * p + 1) * PS;
                    int Ra = wave * 16 + fm;
                    bh8 af = *(const bh8*)(Al + Ra * 32 + (fk ^ (slot_f(Ra) * 8)));
                    bh8 bf[4];
                    #pragma unroll
                    for (int j = 0; j < 4; j++) {
                        int Rb = j * 16 + fm;
                        bf[j] = *(const bh8*)(Bl + Rb * 32 + (fk ^ (slot_f(Rb) * 8)));
                    }
                    #pragma unroll
                    for (int j = 0; j < 4; j++)
                        acc[j] = __builtin_amdgcn_mfma_f32_16x16x32_bf16(af, bf[j], acc[j], 0, 0, 0);
                }
                k0 += 128;
            } else {
                #pragma unroll
                for (int p = 0; p < 2; p++) {
                    long long ra  = (long long)srow * lda + k0 + p * 32 + scq;
                    long long rb2 = (long long)srow * ldb + k0 + p * 32 + scq;
                    GLD16(Ab + ra,  sm + (2 * p) * PS + srow * 32 + schunk);
                    GLD16(Bb + rb2, sm + (2 * p + 1) * PS + srow * 32 + schunk);
                }
                __syncthreads();
                #pragma unroll
                for (int p = 0; p < 2; p++) {
                    const u16* Al = sm + (2 * p) * PS;
                    const u16* Bl = sm + (2 * p + 1) * PS;
                    int Ra = wave * 16 + fm;
                    bh8 af = *(const bh8*)(Al + Ra * 32 + (fk ^ (slot_f(Ra) * 8)));
                    bh8 bf[4];
                    #pragma unroll
                    for (int j = 0; j < 4; j++) {
                        int Rb = j * 16 + fm;
                        bf[j] = *(const bh8*)(Bl + Rb * 32 + (fk ^ (slot_f(Rb) * 8)));
                    }
                    #pragma unroll
                    for (int j = 0; j < 4; j++)
                        acc[j] = __builtin_amdgcn_mfma_f32_16x16x32_bf16(af, bf[j], acc[j], 0, 0, 0);
                }
                k0 += 64;
            }
        }
    }

    int rbase = bm * 64 + wave * 16 + (lane >> 4) * 4;
    int cbase = bn * 64 + (lane & 15);
    long long zoff = bz1 * sC1 + bz2 * sC2;
    if (mode == 1) {
        u16* C = (u16*)Cv + zoff;
        #pragma unroll
        for (int j = 0; j < 4; j++)
            #pragma unroll
            for (int r = 0; r < 4; r++)
                C[(long long)(rbase + r) * ldc + cbase + j * 16] = f2bf(acc[j][r] * alpha);
    } else if (mode == 3) {
        u16* C = (u16*)Cv + zoff;
        #pragma unroll
        for (int j = 0; j < 4; j++)
            #pragma unroll
            for (int r = 0; r < 4; r++) {
                union { _Float16 h; u16 u; } cv;
                cv.h = (_Float16)(acc[j][r] * alpha);
                C[(long long)(rbase + r) * ldc + cbase + j * 16] = cv.u;
            }
    } else if (mode == 5) {
        // par PV + delta: bz1 = batch b, bz2 = chamber ch
        int b = bz1, ch = bz2;
        #pragma unroll
        for (int r = 0; r < 4; r++) {
            int t = rbase + r;
            long long rowg = (long long)b * T_SEQ + t;
            float cf = coefp[(long long)ch * ROWS + rowg];
            #pragma unroll
            for (int j = 0; j < 4; j++) {
                int d = cbase + j * 16;
                float hv = hp[rowg * D_MODEL + d];
                dbp[rowg * KM + ch * D_MODEL + d] = f2bf(cf * (acc[j][r] - hv));
            }
        }
    } else if (mode == 6) {
        __syncthreads();               // staging LDS dead; reuse as transpose tile
        u16* tile = sm;                // [64][66] = 4224 u16, fits
        #pragma unroll
        for (int r = 0; r < 4; r++) {
            int t = rbase + r;
            long long rowg = (long long)bz1 * T_SEQ + t;
            float cf = coefp[rowg];
            int tl = t - bm * 64;
            #pragma unroll
            for (int j = 0; j < 4; j++) {
                int d = cbase + j * 16;
                long long idx = rowg * D_MODEL + d;
                float v = hhfp[idx];
                float nh = v + cf * (acc[j][r] - v);
                hhfp[idx] = nh;
                u16 w = f2bf(nh);
                hbsp[idx] = w;
                tile[((lane & 15) + j * 16) * 66 + tl] = w;
            }
        }
        __syncthreads();
        int dl = tid >> 2, tch = (tid & 3) * 16;
        long long ob = (long long)bz1 * T_SEQ * D_MODEL +
                       (long long)(bn * 64 + dl) * T_SEQ + bm * 64 + tch;
        #pragma unroll
        for (int kk = 0; kk < 16; kk++)
            htsp[ob + kk] = tile[dl * 66 + tch + kk];
    } else {
        float* C = (float*)Cv + zoff;
        #pragma unroll
        for (int j = 0; j < 4; j++)
            #pragma unroll
            for (int r = 0; r < 4; r++)
                C[(long long)(rbase + r) * ldc + cbase + j * 16] = acc[j][r] * alpha;
    }
}

// ---------------------------------------------------------------------------
// LN pre: h = LN(x)*g+b; hhf = h; hbp = hbs = bf16(h)
// ---------------------------------------------------------------------------
__global__ __launch_bounds__(256)
void ln_pre_kernel(const float* __restrict__ x, const float* __restrict__ g,
                   const float* __restrict__ b, float* __restrict__ h,
                   float* __restrict__ hhf, u16* __restrict__ hbp,
                   u16* __restrict__ hbs)
{
    int row = blockIdx.x;
    long long base = (long long)row * D_MODEL;
    int tid = threadIdx.x, lane = tid & 63, wave = tid >> 6;
    __shared__ float red[4];
    float v[3]; float s = 0.f;
    #pragma unroll
    for (int k = 0; k < 3; k++) { v[k] = x[base + tid + k * 256]; s += v[k]; }
    s = wred_sum(s);
    if (lane == 0) red[wave] = s;
    __syncthreads();
    float mean = (red[0] + red[1] + red[2] + red[3]) * (1.f / D_MODEL);
    __syncthreads();
    float sq = 0.f;
    #pragma unroll
    for (int k = 0; k < 3; k++) { float dd = v[k] - mean; sq += dd * dd; }
    sq = wred_sum(sq);
    if (lane == 0) red[wave] = sq;
    __syncthreads();
    float var = (red[0] + red[1] + red[2] + red[3]) * (1.f / D_MODEL);
    float rstd = rsqrtf(var + 1e-5f);
    #pragma unroll
    for (int k = 0; k < 3; k++) {
        int c = tid + k * 256;
        float o = (v[k] - mean) * rstd * g[c] + b[c];
        h[base + c] = o; hhf[base + c] = o;
        u16 w = f2bf(o);
        hbp[base + c] = w; hbs[base + c] = w;
    }
}

// ---------------------------------------------------------------------------
// bf16 transpose, dual output
// ---------------------------------------------------------------------------
__global__ __launch_bounds__(256)
void transpose2_kernel(const u16* __restrict__ hb, u16* __restrict__ htp,
                       u16* __restrict__ hts)
{
    __shared__ u16 tile[32][33];
    int b = blockIdx.z;
    int d0 = blockIdx.x * 32, t0 = blockIdx.y * 32;
    int tx = threadIdx.x & 31, ty = threadIdx.x >> 5;
    long long bb = (long long)b * T_SEQ * D_MODEL;
    #pragma unroll
    for (int i = 0; i < 32; i += 8)
        tile[ty + i][tx] = hb[bb + (long long)(t0 + ty + i) * D_MODEL + d0 + tx];
    __syncthreads();
    #pragma unroll
    for (int i = 0; i < 32; i += 8) {
        long long o = bb + (long long)(d0 + ty + i) * T_SEQ + t0 + tx;
        u16 w = tile[tx][ty + i];
        htp[o] = w; hts[o] = w;
    }
}

// ---------------------------------------------------------------------------
// par coef: gate coefficient per row for all 7 chambers (frozen h)
// ---------------------------------------------------------------------------
__global__ __launch_bounds__(256)
void coef_par_kernel(const float* __restrict__ h, const float* __restrict__ gw,
                     const float* __restrict__ gb, const float* __restrict__ sp,
                     float* __restrict__ coefP)
{
    int row = blockIdx.x * 4 + (threadIdx.x >> 6);
    int lane = threadIdx.x & 63;
    long long base = (long long)row * D_MODEL;
    float hv[12];
    #pragma unroll
    for (int k = 0; k < 12; k++) hv[k] = h[base + lane + 64 * k];
    for (int ci = 0; ci < NCH; ci++) {
        const float* g = gw + ci * D_MODEL;
        float dot = 0.f;
        #pragma unroll
        for (int k = 0; k < 12; k++) dot += hv[k] * g[lane + 64 * k];
        dot = wred_sum(dot);
        if (lane == 0) {
            float gate = 1.f / (1.f + __expf(-(dot + gb[ci])));
            coefP[ci * ROWS + row] = log1pf(expf(sp[ci])) * chamber_mask(ci) * gate;
        }
    }
}

// ---------------------------------------------------------------------------
__global__ __launch_bounds__(256)
void cast4_kernel(const float4* __restrict__ in, ushort4* __restrict__ outp, int n4)
{
    int i = blockIdx.x * 256 + threadIdx.x;
    if (i < n4) {
        float4 v = in[i];
        ushort4 o;
        o.x = f2bf(v.x); o.y = f2bf(v.y); o.z = f2bf(v.z); o.w = f2bf(v.w);
        outp[i] = o;
    }
}

// ---------------------------------------------------------------------------
// final: par = sum of 7 bf16 partial slabs; e = (1-mg)*(hhf-h) + mg*par;
// out = x + rg*(LN(e)*g+b)
// ---------------------------------------------------------------------------
__global__ __launch_bounds__(256)
void final_kernel(const float* __restrict__ x, const float* __restrict__ h,
                  const float* __restrict__ hhf, const u16* __restrict__ Pp,
                  const float* __restrict__ mode_logit, const float* __restrict__ residual_gate,
                  const float* __restrict__ g, const float* __restrict__ b,
                  float* __restrict__ out)
{
    const long long RDe = (long long)ROWS * D_MODEL;
    int row = blockIdx.x;
    long long base = (long long)row * D_MODEL;
    int tid = threadIdx.x, lane = tid & 63, wave = tid >> 6;
    __shared__ float red[4];
    float mg = 1.f / (1.f + __expf(-mode_logit[0]));
    float rg = residual_gate[0];
    float e[3]; float s = 0.f;
    #pragma unroll
    for (int k = 0; k < 3; k++) {
        int c = tid + k * 256;
        float p = 0.f;
        #pragma unroll
        for (int z = 0; z < NCH; z++) p += bf2f(Pp[z * RDe + base + c]);
        float v = (1.f - mg) * (hhf[base + c] - h[base + c]) + mg * p;
        e[k] = v; s += v;
    }
    s = wred_sum(s);
    if (lane == 0) red[wave] = s;
    __syncthreads();
    float mean = (red[0] + red[1] + red[2] + red[3]) * (1.f / D_MODEL);
    __syncthreads();
    float sq = 0.f;
    #pragma unroll
    for (int k = 0; k < 3; k++) { float dd = e[k] - mean; sq += dd * dd; }
    sq = wred_sum(sq);
    if (lane == 0) red[wave] = sq;
    __syncthreads();
    float var = (red[0] + red[1] + red[2] + red[3]) * (1.f / D_MODEL);
    float rstd = rsqrtf(var + 1e-5f);
    #pragma unroll
    for (int k = 0; k < 3; k++) {
        int c = tid + k * 256;
        out[base + c] = x[base + c] + rg * ((e[k] - mean) * rstd * g[c] + b[c]);
    }
}

// ---------------------------------------------------------------------------
extern "C" void kernel_launch(void* const* d_in, const int* in_sizes, int n_in,
                              void* d_out, int out_size, void* d_ws, size_t ws_size,
                              hipStream_t stream)
{
    (void)in_sizes; (void)n_in; (void)out_size; (void)ws_size;
    const float* x             = (const float*)d_in[0];
    const float* Wq            = (const float*)d_in[1];
    const float* Wk            = (const float*)d_in[2];
    const float* gate_w        = (const float*)d_in[3];
    const float* gate_b        = (const float*)d_in[4];
    const float* scale_p       = (const float*)d_in[5];
    const float* merge_W       = (const float*)d_in[6];
    const float* mode_logit    = (const float*)d_in[7];
    const float* residual_gate = (const float*)d_in[8];
    const float* ln_pre_g      = (const float*)d_in[9];
    const float* ln_pre_b      = (const float*)d_in[10];
    const float* ln_post_g     = (const float*)d_in[11];
    const float* ln_post_b     = (const float*)d_in[12];
    float* out = (float*)d_out;

    const long long DD  = (long long)D_MODEL * D_MODEL;   // 589824
    const long long TD  = (long long)T_SEQ * D_MODEL;     // 786432
    const long long TTs = (long long)T_SEQ * T_SEQ;       // 1048576
    const long long RDe = (long long)ROWS * D_MODEL;      // 3145728
    const int NTRI = 16 * 17 / 2;                         // 136 live causal tiles

    size_t off = 0;
    char* wsb = (char*)d_ws;
    auto alloc = [&](size_t bytes) -> void* {
        void* p = wsb + off; off += (bytes + 255) & ~(size_t)255; return p;
    };
    u16*   Mtb  = (u16*)alloc((size_t)NCH * DD * 2);
    u16*   mgb  = (u16*)alloc((size_t)D_MODEL * KM * 2);
    float* h    = (float*)alloc(RDe * 4);
    float* hhf  = (float*)alloc(RDe * 4);
    u16*   hbp  = (u16*)alloc(RDe * 2);
    u16*   htp  = (u16*)alloc(RDe * 2);
    u16*   hbs  = (u16*)alloc(RDe * 2);
    u16*   hts0 = (u16*)alloc(RDe * 2);
    u16*   hts1 = (u16*)alloc(RDe * 2);
    u16*   Spar = (u16*)alloc((size_t)(NCH * BATCH) * TTs * 2);
    u16*   Sseq = (u16*)alloc((size_t)BATCH * TTs * 2);
    u16*   Upar = (u16*)alloc((size_t)NCH * RDe * 2);
    u16*   Useq = (u16*)alloc(RDe * 2);
    u16*   db   = (u16*)alloc((size_t)ROWS * KM * 2);
    float* coefP= (float*)alloc((size_t)NCH * ROWS * 4);
    float* coefS= (float*)alloc((size_t)ROWS * 4);
    // transient aliases (stream-ordered lifetimes):
    u16*   Wqb  = Spar;                 // dead before Spar written
    u16*   Wkb  = Spar + (size_t)NCH * DD;
    u16*   Pp   = Upar;                 // merge partials: Upar dead after par scores

    const float sc = 1.0f / sqrtf((float)D_MODEL);
    const int N4W = (int)((size_t)NCH * DD) / 4;
    const int N4M = (int)((size_t)D_MODEL * KM) / 4;

    ln_pre_kernel<<<ROWS, 256, 0, stream>>>(x, ln_pre_g, ln_pre_b, h, hhf, hbp, hbs);
    cast4_kernel<<<(N4W + 255) / 256, 256, 0, stream>>>((const float4*)Wq, (ushort4*)Wqb, N4W);
    cast4_kernel<<<(N4W + 255) / 256, 256, 0, stream>>>((const float4*)Wk, (ushort4*)Wkb, N4W);
    cast4_kernel<<<(N4M + 255) / 256, 256, 0, stream>>>((const float4*)merge_W, (ushort4*)mgb, N4M);
    transpose2_kernel<<<dim3(24, 32, BATCH), 256, 0, stream>>>(hbp, htp, hts0);
    coef_par_kernel<<<ROWS / 4, 256, 0, stream>>>(h, gate_w, gate_b, scale_p, coefP);

    // Mt_i[d'][d] = sum_e Wk_i[d'][e] Wq_i[d][e]
    gemm_nt_kernel<<<dim3(6, 6, NCH), 256, 0, stream>>>(
        Wkb, Wqb, Mtb, D_MODEL, D_MODEL, D_MODEL, D_MODEL,
        DD, 0, DD, 0, DD, 0, NCH, 1.f, 1, 0, 0, 0, 0);

    // ======================= par branch (frozen h, batched over chambers) ====
    // U_i = hbp @ Mt_i^T  (128-tile, 1344 blocks, swizzled)
    gemm_nt_kernel<<<dim3(6, 32, NCH), 256, 0, stream>>>(
        hbp, Mtb, Upar, D_MODEL, D_MODEL, D_MODEL, D_MODEL,
        0, 0, DD, 0, RDe, 0, NCH, 1.f, 1, 0, 0, 0, 0);
    // scores (64-tile, COMPACT tri: 136 x 28 z = 3808 blocks), raw f16 out
    gemm64_nt_kernel<<<dim3(NTRI * BATCH * NCH), 256, 0, stream>>>(
        Upar, hbp, Spar, D_MODEL, D_MODEL, D_MODEL, T_SEQ,
        TD, RDe, TD, 0, TTs, 4 * TTs, BATCH, sc, 3, 0, 0, NTRI, 0, 0,
        nullptr, nullptr, nullptr, nullptr, nullptr, nullptr);
    // PV + delta (mode 5, FUSED online softmax, LPT): db = bf16(coef*(E - h))
    gemm64_nt_kernel<<<dim3(12, 16, BATCH * NCH), 256, 0, stream>>>(
        Spar, htp, nullptr, T_SEQ, T_SEQ, T_SEQ, D_MODEL,
        TTs, 4 * TTs, TD, 0, 0, 0, BATCH, 1.f, 5, 0, 1, 0, 1, 0,
        nullptr, coefP, nullptr, nullptr, h, db);
    // merge partials: Pp[ch] = d_ch @ Wm_ch^T  (K-slice per z; Pp aliases Upar)
    gemm_nt_kernel<<<dim3(6, 32, NCH), 256, 0, stream>>>(
        db, mgb, Pp, KM, KM, KM, D_MODEL,
        0, 0, 0, 0, RDe, 0, NCH, 1.f, 1, 0, 0, D_MODEL, D_MODEL);

    // ======================= seq branch (serial chain, 64-tile) ==============
    u16* htsCur = hts0;
    u16* htsNxt = hts1;
    for (int i = 0; i < NCH; i++) {
        // U = hbs @ Mt_i^T
        gemm64_nt_kernel<<<dim3(12, 64, 1), 256, 0, stream>>>(
            hbs, Mtb + (long long)i * DD, Useq,
            D_MODEL, D_MODEL, D_MODEL, D_MODEL, 0, 0, 0, 0, 0, 0, 1,
            1.f, 1, 0, 0, 0, 0, 0,
            nullptr, nullptr, nullptr, nullptr, nullptr, nullptr);
        // scores (COMPACT tri 544 blocks) + gate-coef ext (1024 blocks)
        gemm64_nt_kernel<<<dim3(NTRI * BATCH + ROWS / 4), 256, 0, stream>>>(
            Useq, hbs, Sseq, D_MODEL, D_MODEL, D_MODEL, T_SEQ,
            TD, 0, TD, 0, TTs, 0, BATCH, sc, 3, 0, 0, NTRI, /*ci*/ i,
            /*ntri_blk*/ NTRI * BATCH,
            /*coefS out*/ coefS, /*hhf*/ hhf, (u16*)gate_w, (u16*)gate_b,
            scale_p, nullptr);
        // PV + delta (mode 6, FUSED online softmax, LPT): hh' = hh + coef*(E-hh)
        gemm64_nt_kernel<<<dim3(12, 16, BATCH), 256, 0, stream>>>(
            Sseq, htsCur, nullptr, T_SEQ, T_SEQ, T_SEQ, D_MODEL,
            TTs, 0, TD, 0, 0, 0, BATCH, 1.f, 6, 0, 1, 0, 1, 0,
            hhf, coefS, hbs, htsNxt, nullptr, nullptr);
        u16* tmp = htsCur; htsCur = htsNxt; htsNxt = tmp;
    }

    final_kernel<<<ROWS, 256, 0, stream>>>(x, h, hhf, Pp, mode_logit, residual_gate,
                                           ln_post_g, ln_post_b, out);
}

// Round 10
// 763.204 us; speedup vs baseline: 7.4126x; 1.1365x over previous
//
#include <hip/hip_runtime.h>
#include <math.h>

#define D_MODEL 768
#define T_SEQ   1024
#define BATCH   4
#define NCH     7
#define ROWS    4096            // BATCH*T_SEQ
#define KM      (NCH * D_MODEL) // 5376

typedef unsigned short u16;
typedef __attribute__((ext_vector_type(8))) short bh8;   // 8 x bf16
typedef __attribute__((ext_vector_type(4))) float f32x4;

__device__ __forceinline__ u16 f2bf(float f) {
    union { float f; unsigned u; } v; v.f = f;
    return (u16)((v.u + 0x7fffu + ((v.u >> 16) & 1u)) >> 16);  // RNE
}
__device__ __forceinline__ float bf2f(u16 b) {
    union { unsigned u; float f; } v; v.u = ((unsigned)b) << 16;
    return v.f;
}
__device__ __forceinline__ float wred_sum(float v) {
    #pragma unroll
    for (int o = 32; o; o >>= 1) v += __shfl_down(v, o, 64);
    return v;
}
__device__ __forceinline__ float wred_max(float v) {
    #pragma unroll
    for (int o = 32; o; o >>= 1) v = fmaxf(v, __shfl_down(v, o, 64));
    return v;
}
__device__ __forceinline__ float chamber_mask(int i) {
    float slope = 8.0f * 7.0f / 2000.0f;
    return 1.0f / (1.0f + __expf(-slope * (4000.0f - 2000.0f * (i + 0.5f) / 7.0f)));
}

#define GLD16(g, l) __builtin_amdgcn_global_load_lds( \
    (const __attribute__((address_space(1))) void*)(g), \
    (__attribute__((address_space(3))) void*)(l), 16, 0, 0)

// XCD-aware swizzle (identity when N not divisible by 8).
__device__ __forceinline__ int xcd_swizzle(int gflat, int Ntot) {
    if ((Ntot & 7) == 0) {
        int chunk = Ntot >> 3;
        gflat = (gflat & 7) * chunk + (gflat >> 3);
    }
    return gflat;
}

// LDS slot swizzle — gemm64 ONLY (A/B across rounds: helps LDS-read-bound
// gemm64; hurts stage-bound gemm128 by ~10%).
// Dead ends banked: in-kernel grid sync (130-190us/barrier, R7/R8);
// flash softmax fusion (VALU-bound, R9); horizontal multi-problem fusion (R1).
__device__ __forceinline__ int slot_f(int row) { return (row >> 1) & 3; }

// ---------------------------------------------------------------------------
// 128x128-tile NT GEMM: C = alpha * A[M,K] * B[N,K]^T  (bf16 in)
// K=64 per barrier as TWO independent BK=32 panels; XCD tile swizzle.
// mode: 0 f32 store, 1 bf16 store, 3 f16 store
// kss/klen: K slice per bz1 (merge partials). All K extents multiple of 64.
// ---------------------------------------------------------------------------
__global__ __launch_bounds__(256)
void gemm_nt_kernel(const u16* __restrict__ A, const u16* __restrict__ B,
                    void* __restrict__ Cv,
                    int K, int lda, int ldb, int ldc,
                    long long sA1, long long sA2, long long sB1, long long sB2,
                    long long sC1, long long sC2, int zm,
                    float alpha, int mode, int causal_skip, int causal_k,
                    int kss, int klen)
{
    int gx = gridDim.x, gy = gridDim.y;
    int Ntot = gx * gy * gridDim.z;
    int gflat = xcd_swizzle(blockIdx.x + gx * (blockIdx.y + gy * blockIdx.z), Ntot);
    int bn = gflat % gx;
    int rest = gflat / gx;
    int bm = rest % gy;
    int bz = rest / gy;
    if (causal_skip && bn > bm) return;
    int bz1 = bz % zm, bz2 = bz / zm;

    const u16* Ab = A + bz1 * sA1 + bz2 * sA2 + (long long)(bm * 128) * lda;
    const u16* Bb = B + bz1 * sB1 + bz2 * sB2 + (long long)(bn * 128) * ldb;

    __shared__ u16 sm[4 * 128 * 32];   // 32 KB: A0|B0|A1|B1 panels
    u16* Al0 = sm;
    u16* Bl0 = sm + 128 * 32;
    u16* Al1 = sm + 2 * 128 * 32;
    u16* Bl1 = sm + 3 * 128 * 32;

    int tid  = threadIdx.x;
    int lane = tid & 63;
    int wave = tid >> 6;
    int wm = wave >> 1, wn = wave & 1;

    int k_begin = kss ? bz1 * kss : 0;
    int k_end   = klen ? (k_begin + klen) : K;
    if (causal_k) k_end = min(k_end, (bm + 1) * 128);

    f32x4 acc[4][4];
    #pragma unroll
    for (int i = 0; i < 4; i++)
        #pragma unroll
        for (int j = 0; j < 4; j++)
            acc[i][j] = (f32x4){0.f, 0.f, 0.f, 0.f};

    int srow = lane >> 2;
    int skq  = (lane & 3) * 8;
    int fm   = lane & 15;
    int fk   = (lane >> 4) * 8;

    for (int k0 = k_begin; k0 < k_end; k0 += 64) {
        __syncthreads();
        #pragma unroll
        for (int r = 0; r < 2; r++) {
            int row = r * 64 + wave * 16 + srow;
            long long ra = (long long)row * lda + k0 + skq;
            long long rb2 = (long long)row * ldb + k0 + skq;
            GLD16(Ab + ra,       Al0 + row * 32 + skq);
            GLD16(Bb + rb2,      Bl0 + row * 32 + skq);
            GLD16(Ab + ra + 32,  Al1 + row * 32 + skq);
            GLD16(Bb + rb2 + 32, Bl1 + row * 32 + skq);
        }
        __syncthreads();

        #pragma unroll
        for (int p = 0; p < 2; p++) {
            const u16* Al = p ? Al1 : Al0;
            const u16* Bl = p ? Bl1 : Bl0;
            bh8 af[4], bf[4];
            #pragma unroll
            for (int i = 0; i < 4; i++)
                af[i] = *(const bh8*)(Al + (wm * 64 + i * 16 + fm) * 32 + fk);
            #pragma unroll
            for (int j = 0; j < 4; j++)
                bf[j] = *(const bh8*)(Bl + (wn * 64 + j * 16 + fm) * 32 + fk);
            #pragma unroll
            for (int i = 0; i < 4; i++)
                #pragma unroll
                for (int j = 0; j < 4; j++)
                    acc[i][j] = __builtin_amdgcn_mfma_f32_16x16x32_bf16(af[i], bf[j], acc[i][j], 0, 0, 0);
        }
    }

    int rbase = bm * 128 + wm * 64 + (lane >> 4) * 4;
    int cbase = bn * 128 + wn * 64 + (lane & 15);
    long long zoff = bz1 * sC1 + bz2 * sC2;
    if (mode == 1) {
        u16* C = (u16*)Cv + zoff;
        #pragma unroll
        for (int i = 0; i < 4; i++)
            #pragma unroll
            for (int j = 0; j < 4; j++)
                #pragma unroll
                for (int r = 0; r < 4; r++)
                    C[(long long)(rbase + i * 16 + r) * ldc + cbase + j * 16] = f2bf(acc[i][j][r] * alpha);
    } else if (mode == 3) {
        u16* C = (u16*)Cv + zoff;
        #pragma unroll
        for (int i = 0; i < 4; i++)
            #pragma unroll
            for (int j = 0; j < 4; j++)
                #pragma unroll
                for (int r = 0; r < 4; r++) {
                    union { _Float16 h; u16 u; } cv;
                    cv.h = (_Float16)(acc[i][j][r] * alpha);
                    C[(long long)(rbase + i * 16 + r) * ldc + cbase + j * 16] = cv.u;
                }
    } else {
        float* C = (float*)Cv + zoff;
        #pragma unroll
        for (int i = 0; i < 4; i++)
            #pragma unroll
            for (int j = 0; j < 4; j++)
                #pragma unroll
                for (int r = 0; r < 4; r++)
                    C[(long long)(rbase + i * 16 + r) * ldc + cbase + j * 16] = acc[i][j][r] * alpha;
    }
}

// ---------------------------------------------------------------------------
// 64x64-tile NT GEMM — K=128 per barrier as FOUR BK=32 panels (2-panel tail).
// XCD tile swizzle + LDS slot swizzle. tri: compact triangular launch.
// lptrev: heavy causal-K tiles first.
// mode: 0 f32, 1 bf16, 3 f16, 5 par PV+delta, 6 seq PV+delta.
// ---------------------------------------------------------------------------
__global__ __launch_bounds__(256)
void gemm64_nt_kernel(const u16* __restrict__ A, const u16* __restrict__ B,
                      void* __restrict__ Cv,
                      int K, int lda, int ldb, int ldc,
                      long long sA1, long long sA2, long long sB1, long long sB2,
                      long long sC1, long long sC2, int zm,
                      float alpha, int mode, int causal_skip, int causal_k,
                      int tri, int lptrev,
                      float* __restrict__ hhfp, const float* __restrict__ coefp,
                      u16* __restrict__ hbsp, u16* __restrict__ htsp,
                      const float* __restrict__ hp, u16* __restrict__ dbp)
{
    int bn, bm, bz;
    if (tri) {
        int Ntot = gridDim.x;
        int f = xcd_swizzle(blockIdx.x, Ntot);
        bz = f / tri;
        int r = f - bz * tri;
        bm = (int)((sqrtf(8.0f * (float)r + 1.0f) - 1.0f) * 0.5f);
        while ((bm + 1) * (bm + 2) / 2 <= r) bm++;
        while (bm * (bm + 1) / 2 > r) bm--;
        bn = r - bm * (bm + 1) / 2;
    } else {
        int gx = gridDim.x, gy = gridDim.y;
        int Ntot = gx * gy * gridDim.z;
        int gflat = xcd_swizzle(blockIdx.x + gx * (blockIdx.y + gy * blockIdx.z), Ntot);
        bn = gflat % gx;
        int rest = gflat / gx;
        bm = rest % gy;
        bz = rest / gy;
        if (lptrev) bm = gy - 1 - bm;      // heavy causal-K tiles first
        if (causal_skip && bn > bm) return;
    }
    int bz1 = bz % zm, bz2 = bz / zm;

    const u16* Ab = A + bz1 * sA1 + bz2 * sA2 + (long long)(bm * 64) * lda;
    const u16* Bb = B + bz1 * sB1 + bz2 * sB2 + (long long)(bn * 64) * ldb;

    __shared__ u16 sm[8 * 64 * 32];    // 32 KB: A0 B0 A1 B1 A2 B2 A3 B3
    const int PS = 64 * 32;            // panel stride (2048 u16)

    int tid  = threadIdx.x;
    int lane = tid & 63;
    int wave = tid >> 6;

    int k_end = causal_k ? min(K, (bm + 1) * 64) : K;

    f32x4 acc[4];
    #pragma unroll
    for (int j = 0; j < 4; j++) acc[j] = (f32x4){0.f, 0.f, 0.f, 0.f};

    int srow   = tid >> 2;             // 0..63
    int schunk = (tid & 3) * 8;
    int scq    = ((tid & 3) ^ slot_f(srow)) * 8;   // swizzled global chunk
    int fm     = lane & 15;
    int fk     = (lane >> 4) * 8;

    int k0 = 0;
    while (k0 < k_end) {
        __syncthreads();
        if (k_end - k0 >= 128) {
            #pragma unroll
            for (int p = 0; p < 4; p++) {
                long long ra  = (long long)srow * lda + k0 + p * 32 + scq;
                long long rb2 = (long long)srow * ldb + k0 + p * 32 + scq;
                GLD16(Ab + ra,  sm + (2 * p) * PS + srow * 32 + schunk);
                GLD16(Bb + rb2, sm + (2 * p + 1) * PS + srow * 32 + schunk);
            }
            __syncthreads();
            #pragma unroll
            for (int p = 0; p < 4; p++) {
                const u16* Al = sm + (2 * p) * PS;
                const u16* Bl = sm + (2 * p + 1) * PS;
                int Ra = wave * 16 + fm;
                bh8 af = *(const bh8*)(Al + Ra * 32 + (fk ^ (slot_f(Ra) * 8)));
                bh8 bf[4];
                #pragma unroll
                for (int j = 0; j < 4; j++) {
                    int Rb = j * 16 + fm;
                    bf[j] = *(const bh8*)(Bl + Rb * 32 + (fk ^ (slot_f(Rb) * 8)));
                }
                #pragma unroll
                for (int j = 0; j < 4; j++)
                    acc[j] = __builtin_amdgcn_mfma_f32_16x16x32_bf16(af, bf[j], acc[j], 0, 0, 0);
            }
            k0 += 128;
        } else {
            #pragma unroll
            for (int p = 0; p < 2; p++) {
                long long ra  = (long long)srow * lda + k0 + p * 32 + scq;
                long long rb2 = (long long)srow * ldb + k0 + p * 32 + scq;
                GLD16(Ab + ra,  sm + (2 * p) * PS + srow * 32 + schunk);
                GLD16(Bb + rb2, sm + (2 * p + 1) * PS + srow * 32 + schunk);
            }
            __syncthreads();
            #pragma unroll
            for (int p = 0; p < 2; p++) {
                const u16* Al = sm + (2 * p) * PS;
                const u16* Bl = sm + (2 * p + 1) * PS;
                int Ra = wave * 16 + fm;
                bh8 af = *(const bh8*)(Al + Ra * 32 + (fk ^ (slot_f(Ra) * 8)));
                bh8 bf[4];
                #pragma unroll
                for (int j = 0; j < 4; j++) {
                    int Rb = j * 16 + fm;
                    bf[j] = *(const bh8*)(Bl + Rb * 32 + (fk ^ (slot_f(Rb) * 8)));
                }
                #pragma unroll
                for (int j = 0; j < 4; j++)
                    acc[j] = __builtin_amdgcn_mfma_f32_16x16x32_bf16(af, bf[j], acc[j], 0, 0, 0);
            }
            k0 += 64;
        }
    }

    int rbase = bm * 64 + wave * 16 + (lane >> 4) * 4;
    int cbase = bn * 64 + (lane & 15);
    long long zoff = bz1 * sC1 + bz2 * sC2;
    if (mode == 1) {
        u16* C = (u16*)Cv + zoff;
        #pragma unroll
        for (int j = 0; j < 4; j++)
            #pragma unroll
            for (int r = 0; r < 4; r++)
                C[(long long)(rbase + r) * ldc + cbase + j * 16] = f2bf(acc[j][r] * alpha);
    } else if (mode == 3) {
        u16* C = (u16*)Cv + zoff;
        #pragma unroll
        for (int j = 0; j < 4; j++)
            #pragma unroll
            for (int r = 0; r < 4; r++) {
                union { _Float16 h; u16 u; } cv;
                cv.h = (_Float16)(acc[j][r] * alpha);
                C[(long long)(rbase + r) * ldc + cbase + j * 16] = cv.u;
            }
    } else if (mode == 5) {
        // par PV + delta: bz1 = batch b, bz2 = chamber ch
        int b = bz1, ch = bz2;
        #pragma unroll
        for (int r = 0; r < 4; r++) {
            int t = rbase + r;
            long long rowg = (long long)b * T_SEQ + t;
            float cf = coefp[(long long)ch * ROWS + rowg];
            #pragma unroll
            for (int j = 0; j < 4; j++) {
                int d = cbase + j * 16;
                float hv = hp[rowg * D_MODEL + d];
                dbp[rowg * KM + ch * D_MODEL + d] = f2bf(cf * (acc[j][r] - hv));
            }
        }
    } else if (mode == 6) {
        __syncthreads();               // staging LDS dead; reuse as transpose tile
        u16* tile = sm;                // [64][66] = 4224 u16, fits
        #pragma unroll
        for (int r = 0; r < 4; r++) {
            int t = rbase + r;
            long long rowg = (long long)bz1 * T_SEQ + t;
            float cf = coefp[rowg];
            int tl = t - bm * 64;
            #pragma unroll
            for (int j = 0; j < 4; j++) {
                int d = cbase + j * 16;
                long long idx = rowg * D_MODEL + d;
                float v = hhfp[idx];
                float nh = v + cf * (acc[j][r] - v);
                hhfp[idx] = nh;
                u16 w = f2bf(nh);
                hbsp[idx] = w;
                tile[((lane & 15) + j * 16) * 66 + tl] = w;
            }
        }
        __syncthreads();
        int dl = tid >> 2, tch = (tid & 3) * 16;
        long long ob = (long long)bz1 * T_SEQ * D_MODEL +
                       (long long)(bn * 64 + dl) * T_SEQ + bm * 64 + tch;
        #pragma unroll
        for (int kk = 0; kk < 16; kk++)
            htsp[ob + kk] = tile[dl * 66 + tch + kk];
    } else {
        float* C = (float*)Cv + zoff;
        #pragma unroll
        for (int j = 0; j < 4; j++)
            #pragma unroll
            for (int r = 0; r < 4; r++)
                C[(long long)(rbase + r) * ldc + cbase + j * 16] = acc[j][r] * alpha;
    }
}

// ---------------------------------------------------------------------------
// LN pre + FUSED par gate-coefs: h = LN(x)*g+b; hhf = h; hbp = hbs = bf16(h);
// coefP[ci][row] = softplus(sp[ci])*mask(ci)*sigmoid(dot(h_row, gw_ci)+gb[ci])
// (h row already in registers — removes the coef_par dispatch + boundary;
//  reduction order differs from the old kernel by ~1e-7 relative, absmax
//  headroom 0.0156 vs 0.09)
// ---------------------------------------------------------------------------
__global__ __launch_bounds__(256)
void ln_pre_kernel(const float* __restrict__ x, const float* __restrict__ g,
                   const float* __restrict__ b, float* __restrict__ h,
                   float* __restrict__ hhf, u16* __restrict__ hbp,
                   u16* __restrict__ hbs,
                   const float* __restrict__ gw, const float* __restrict__ gb,
                   const float* __restrict__ sp, float* __restrict__ coefP)
{
    int row = blockIdx.x;
    long long base = (long long)row * D_MODEL;
    int tid = threadIdx.x, lane = tid & 63, wave = tid >> 6;
    __shared__ float red[4];
    float v[3]; float s = 0.f;
    #pragma unroll
    for (int k = 0; k < 3; k++) { v[k] = x[base + tid + k * 256]; s += v[k]; }
    s = wred_sum(s);
    if (lane == 0) red[wave] = s;
    __syncthreads();
    float mean = (red[0] + red[1] + red[2] + red[3]) * (1.f / D_MODEL);
    __syncthreads();
    float sq = 0.f;
    #pragma unroll
    for (int k = 0; k < 3; k++) { float dd = v[k] - mean; sq += dd * dd; }
    sq = wred_sum(sq);
    if (lane == 0) red[wave] = sq;
    __syncthreads();
    float var = (red[0] + red[1] + red[2] + red[3]) * (1.f / D_MODEL);
    float rstd = rsqrtf(var + 1e-5f);
    #pragma unroll
    for (int k = 0; k < 3; k++) {
        int c = tid + k * 256;
        float o = (v[k] - mean) * rstd * g[c] + b[c];
        v[k] = o;                      // keep normalized value for coef dots
        h[base + c] = o; hhf[base + c] = o;
        u16 w = f2bf(o);
        hbp[base + c] = w; hbs[base + c] = w;
    }
    // fused par gate-coefs (7 chambers)
    for (int ci = 0; ci < NCH; ci++) {
        __syncthreads();               // red[] free from previous use
        float dot = 0.f;
        #pragma unroll
        for (int k = 0; k < 3; k++)
            dot += v[k] * gw[ci * D_MODEL + tid + k * 256];
        dot = wred_sum(dot);
        if (lane == 0) red[wave] = dot;
        __syncthreads();
        if (tid == 0) {
            float tot = red[0] + red[1] + red[2] + red[3];
            float gate = 1.f / (1.f + __expf(-(tot + gb[ci])));
            coefP[ci * ROWS + row] = log1pf(expf(sp[ci])) * chamber_mask(ci) * gate;
        }
    }
}

// ---------------------------------------------------------------------------
// bf16 transpose, dual output
// ---------------------------------------------------------------------------
__global__ __launch_bounds__(256)
void transpose2_kernel(const u16* __restrict__ hb, u16* __restrict__ htp,
                       u16* __restrict__ hts)
{
    __shared__ u16 tile[32][33];
    int b = blockIdx.z;
    int d0 = blockIdx.x * 32, t0 = blockIdx.y * 32;
    int tx = threadIdx.x & 31, ty = threadIdx.x >> 5;
    long long bb = (long long)b * T_SEQ * D_MODEL;
    #pragma unroll
    for (int i = 0; i < 32; i += 8)
        tile[ty + i][tx] = hb[bb + (long long)(t0 + ty + i) * D_MODEL + d0 + tx];
    __syncthreads();
    #pragma unroll
    for (int i = 0; i < 32; i += 8) {
        long long o = bb + (long long)(d0 + ty + i) * T_SEQ + t0 + tx;
        u16 w = tile[tx][ty + i];
        htp[o] = w; hts[o] = w;
    }
}

// ---------------------------------------------------------------------------
// causal softmax, f16 in -> bf16 out, in place
// ---------------------------------------------------------------------------
__device__ __forceinline__ void softmax_row(u16* row, int len, int tid, int lane, int wave,
                                            float* red)
{
    float ev[4];
    float m = -3.0e38f;
    #pragma unroll
    for (int k = 0; k < 4; k++) {
        int s = tid + k * 256;
        if (s < len) {
            union { u16 u; _Float16 h; } cv; cv.u = row[s];
            ev[k] = (float)cv.h;
        } else ev[k] = -3.0e38f;
        m = fmaxf(m, ev[k]);
    }
    m = wred_max(m);
    if (lane == 0) red[wave] = m;
    __syncthreads();
    m = fmaxf(fmaxf(red[0], red[1]), fmaxf(red[2], red[3]));
    __syncthreads();
    float sum = 0.f;
    #pragma unroll
    for (int k = 0; k < 4; k++) {
        int s = tid + k * 256;
        float e = (s < len) ? __expf(ev[k] - m) : 0.f;
        ev[k] = e; sum += e;
    }
    sum = wred_sum(sum);
    if (lane == 0) red[wave] = sum;
    __syncthreads();
    sum = red[0] + red[1] + red[2] + red[3];
    float inv = 1.f / sum;
    #pragma unroll
    for (int k = 0; k < 4; k++)
        row[tid + k * 256] = f2bf(ev[k] * inv);
}

__global__ __launch_bounds__(256)
void softmax_kernel(u16* __restrict__ SP)
{
    int t = blockIdx.x, z = blockIdx.y;
    __shared__ float red[4];
    int tid = threadIdx.x, lane = tid & 63, wave = tid >> 6;
    softmax_row(SP + (long long)z * T_SEQ * T_SEQ + (long long)t * T_SEQ,
                t + 1, tid, lane, wave, red);
}

// seq softmax + fused coef slice (z == BATCH computes gate coefs for 4 rows)
__global__ __launch_bounds__(256)
void softmax_coef_kernel(u16* __restrict__ SP, const float* __restrict__ hhf,
                         const float* __restrict__ gw, const float* __restrict__ gb,
                         const float* __restrict__ sp, int ci,
                         float* __restrict__ coefS)
{
    int t = blockIdx.x, z = blockIdx.y;
    int tid = threadIdx.x, lane = tid & 63, wave = tid >> 6;
    if (z == BATCH) {
        int row = t * 4 + wave;
        long long base = (long long)row * D_MODEL;
        const float* g = gw + ci * D_MODEL;
        float dot = 0.f;
        #pragma unroll
        for (int k = 0; k < 12; k++) dot += hhf[base + lane + 64 * k] * g[lane + 64 * k];
        dot = wred_sum(dot);
        if (lane == 0) {
            float gate = 1.f / (1.f + __expf(-(dot + gb[ci])));
            coefS[row] = log1pf(expf(sp[ci])) * chamber_mask(ci) * gate;
        }
        return;
    }
    __shared__ float red[4];
    softmax_row(SP + (long long)z * T_SEQ * T_SEQ + (long long)t * T_SEQ,
                t + 1, tid, lane, wave, red);
}

// ---------------------------------------------------------------------------
// 3-range f32 -> bf16 cast (merges the old 3 cast4 dispatches into one)
// ---------------------------------------------------------------------------
__global__ __launch_bounds__(256)
void cast4x3_kernel(const float4* __restrict__ a, ushort4* __restrict__ oa, int na,
                    const float4* __restrict__ b, ushort4* __restrict__ ob, int nb,
                    const float4* __restrict__ c, ushort4* __restrict__ oc, int nc)
{
    int i = blockIdx.x * 256 + threadIdx.x;
    const float4* src; ushort4* dst;
    if (i < na) { src = a; dst = oa; }
    else if ((i -= na) < nb) { src = b; dst = ob; }
    else if ((i -= nb) < nc) { src = c; dst = oc; }
    else return;
    float4 v = src[i];
    ushort4 o;
    o.x = f2bf(v.x); o.y = f2bf(v.y); o.z = f2bf(v.z); o.w = f2bf(v.w);
    dst[i] = o;
}

// ---------------------------------------------------------------------------
// final: par = sum of 7 bf16 partial slabs; e = (1-mg)*(hhf-h) + mg*par;
// out = x + rg*(LN(e)*g+b)
// ---------------------------------------------------------------------------
__global__ __launch_bounds__(256)
void final_kernel(const float* __restrict__ x, const float* __restrict__ h,
                  const float* __restrict__ hhf, const u16* __restrict__ Pp,
                  const float* __restrict__ mode_logit, const float* __restrict__ residual_gate,
                  const float* __restrict__ g, const float* __restrict__ b,
                  float* __restrict__ out)
{
    const long long RDe = (long long)ROWS * D_MODEL;
    int row = blockIdx.x;
    long long base = (long long)row * D_MODEL;
    int tid = threadIdx.x, lane = tid & 63, wave = tid >> 6;
    __shared__ float red[4];
    float mg = 1.f / (1.f + __expf(-mode_logit[0]));
    float rg = residual_gate[0];
    float e[3]; float s = 0.f;
    #pragma unroll
    for (int k = 0; k < 3; k++) {
        int c = tid + k * 256;
        float p = 0.f;
        #pragma unroll
        for (int z = 0; z < NCH; z++) p += bf2f(Pp[z * RDe + base + c]);
        float v = (1.f - mg) * (hhf[base + c] - h[base + c]) + mg * p;
        e[k] = v; s += v;
    }
    s = wred_sum(s);
    if (lane == 0) red[wave] = s;
    __syncthreads();
    float mean = (red[0] + red[1] + red[2] + red[3]) * (1.f / D_MODEL);
    __syncthreads();
    float sq = 0.f;
    #pragma unroll
    for (int k = 0; k < 3; k++) { float dd = e[k] - mean; sq += dd * dd; }
    sq = wred_sum(sq);
    if (lane == 0) red[wave] = sq;
    __syncthreads();
    float var = (red[0] + red[1] + red[2] + red[3]) * (1.f / D_MODEL);
    float rstd = rsqrtf(var + 1e-5f);
    #pragma unroll
    for (int k = 0; k < 3; k++) {
        int c = tid + k * 256;
        out[base + c] = x[base + c] + rg * ((e[k] - mean) * rstd * g[c] + b[c]);
    }
}

// ---------------------------------------------------------------------------
extern "C" void kernel_launch(void* const* d_in, const int* in_sizes, int n_in,
                              void* d_out, int out_size, void* d_ws, size_t ws_size,
                              hipStream_t stream)
{
    (void)in_sizes; (void)n_in; (void)out_size; (void)ws_size;
    const float* x             = (const float*)d_in[0];
    const float* Wq            = (const float*)d_in[1];
    const float* Wk            = (const float*)d_in[2];
    const float* gate_w        = (const float*)d_in[3];
    const float* gate_b        = (const float*)d_in[4];
    const float* scale_p       = (const float*)d_in[5];
    const float* merge_W       = (const float*)d_in[6];
    const float* mode_logit    = (const float*)d_in[7];
    const float* residual_gate = (const float*)d_in[8];
    const float* ln_pre_g      = (const float*)d_in[9];
    const float* ln_pre_b      = (const float*)d_in[10];
    const float* ln_post_g     = (const float*)d_in[11];
    const float* ln_post_b     = (const float*)d_in[12];
    float* out = (float*)d_out;

    const long long DD  = (long long)D_MODEL * D_MODEL;   // 589824
    const long long TD  = (long long)T_SEQ * D_MODEL;     // 786432
    const long long TTs = (long long)T_SEQ * T_SEQ;       // 1048576
    const long long RDe = (long long)ROWS * D_MODEL;      // 3145728
    const int NTRI = 16 * 17 / 2;                         // 136 live causal tiles

    size_t off = 0;
    char* wsb = (char*)d_ws;
    auto alloc = [&](size_t bytes) -> void* {
        void* p = wsb + off; off += (bytes + 255) & ~(size_t)255; return p;
    };
    u16*   Mtb  = (u16*)alloc((size_t)NCH * DD * 2);
    u16*   mgb  = (u16*)alloc((size_t)D_MODEL * KM * 2);
    float* h    = (float*)alloc(RDe * 4);
    float* hhf  = (float*)alloc(RDe * 4);
    u16*   hbp  = (u16*)alloc(RDe * 2);
    u16*   htp  = (u16*)alloc(RDe * 2);
    u16*   hbs  = (u16*)alloc(RDe * 2);
    u16*   hts0 = (u16*)alloc(RDe * 2);
    u16*   hts1 = (u16*)alloc(RDe * 2);
    u16*   Spar = (u16*)alloc((size_t)(NCH * BATCH) * TTs * 2);
    u16*   Sseq = (u16*)alloc((size_t)BATCH * TTs * 2);
    u16*   Upar = (u16*)alloc((size_t)NCH * RDe * 2);
    u16*   Useq = (u16*)alloc(RDe * 2);
    u16*   db   = (u16*)alloc((size_t)ROWS * KM * 2);
    float* coefP= (float*)alloc((size_t)NCH * ROWS * 4);
    float* coefS= (float*)alloc((size_t)ROWS * 4);
    // transient aliases (stream-ordered lifetimes):
    u16*   Wqb  = Spar;                 // dead before Spar written
    u16*   Wkb  = Spar + (size_t)NCH * DD;
    u16*   Pp   = Upar;                 // merge partials: Upar dead after par scores

    const float sc = 1.0f / sqrtf((float)D_MODEL);
    const int N4W = (int)((size_t)NCH * DD) / 4;
    const int N4M = (int)((size_t)D_MODEL * KM) / 4;
    const int N4T = N4W + N4W + N4M;

    ln_pre_kernel<<<ROWS, 256, 0, stream>>>(x, ln_pre_g, ln_pre_b, h, hhf, hbp, hbs,
                                            gate_w, gate_b, scale_p, coefP);
    cast4x3_kernel<<<(N4T + 255) / 256, 256, 0, stream>>>(
        (const float4*)Wq, (ushort4*)Wqb, N4W,
        (const float4*)Wk, (ushort4*)Wkb, N4W,
        (const float4*)merge_W, (ushort4*)mgb, N4M);
    transpose2_kernel<<<dim3(24, 32, BATCH), 256, 0, stream>>>(hbp, htp, hts0);

    // Mt_i[d'][d] = sum_e Wk_i[d'][e] Wq_i[d][e]
    gemm_nt_kernel<<<dim3(6, 6, NCH), 256, 0, stream>>>(
        Wkb, Wqb, Mtb, D_MODEL, D_MODEL, D_MODEL, D_MODEL,
        DD, 0, DD, 0, DD, 0, NCH, 1.f, 1, 0, 0, 0, 0);

    // ======================= par branch (frozen h, batched over chambers) ====
    // U_i = hbp @ Mt_i^T  (128-tile, 1344 blocks, swizzled)
    gemm_nt_kernel<<<dim3(6, 32, NCH), 256, 0, stream>>>(
        hbp, Mtb, Upar, D_MODEL, D_MODEL, D_MODEL, D_MODEL,
        0, 0, DD, 0, RDe, 0, NCH, 1.f, 1, 0, 0, 0, 0);
    // scores (64-tile, COMPACT: 136 live tiles x 28 z = 3808 blocks)
    gemm64_nt_kernel<<<dim3(NTRI * BATCH * NCH), 256, 0, stream>>>(
        Upar, hbp, Spar, D_MODEL, D_MODEL, D_MODEL, T_SEQ,
        TD, RDe, TD, 0, TTs, 4 * TTs, BATCH, sc, 3, 0, 0, NTRI, 0,
        nullptr, nullptr, nullptr, nullptr, nullptr, nullptr);
    softmax_kernel<<<dim3(T_SEQ, BATCH * NCH), 256, 0, stream>>>(Spar);
    // PV + delta (64-tile mode 5, LPT heavy-first): db = bf16(coef*(E - h))
    gemm64_nt_kernel<<<dim3(12, 16, BATCH * NCH), 256, 0, stream>>>(
        Spar, htp, nullptr, T_SEQ, T_SEQ, T_SEQ, D_MODEL,
        TTs, 4 * TTs, TD, 0, 0, 0, BATCH, 1.f, 5, 0, 1, 0, 1,
        nullptr, coefP, nullptr, nullptr, h, db);
    // merge partials: Pp[ch] = d_ch @ Wm_ch^T  (K-slice per z; Pp aliases Upar)
    gemm_nt_kernel<<<dim3(6, 32, NCH), 256, 0, stream>>>(
        db, mgb, Pp, KM, KM, KM, D_MODEL,
        0, 0, 0, 0, RDe, 0, NCH, 1.f, 1, 0, 0, D_MODEL, D_MODEL);

    // ======================= seq branch (serial chain, 64-tile) ==============
    u16* htsCur = hts0;
    u16* htsNxt = hts1;
    for (int i = 0; i < NCH; i++) {
        // U = hbs @ Mt_i^T
        gemm64_nt_kernel<<<dim3(12, 64, 1), 256, 0, stream>>>(
            hbs, Mtb + (long long)i * DD, Useq,
            D_MODEL, D_MODEL, D_MODEL, D_MODEL, 0, 0, 0, 0, 0, 0, 1,
            1.f, 1, 0, 0, 0, 0,
            nullptr, nullptr, nullptr, nullptr, nullptr, nullptr);
        // scores: COMPACT 136 live tiles x 4 batches = 544 blocks, uniform work
        gemm64_nt_kernel<<<dim3(NTRI * BATCH), 256, 0, stream>>>(
            Useq, hbs, Sseq, D_MODEL, D_MODEL, D_MODEL, T_SEQ,
            TD, 0, TD, 0, TTs, 0, BATCH, sc, 3, 0, 0, NTRI, 0,
            nullptr, nullptr, nullptr, nullptr, nullptr, nullptr);
        // softmax + fused gate-coef slice (z == BATCH)
        softmax_coef_kernel<<<dim3(T_SEQ, BATCH + 1), 256, 0, stream>>>(
            Sseq, hhf, gate_w, gate_b, scale_p, i, coefS);
        // PV + delta (mode 6, LPT heavy-first): hh' = hh + coef*(E-hh)
        gemm64_nt_kernel<<<dim3(12, 16, BATCH), 256, 0, stream>>>(
            Sseq, htsCur, nullptr, T_SEQ, T_SEQ, T_SEQ, D_MODEL,
            TTs, 0, TD, 0, 0, 0, BATCH, 1.f, 6, 0, 1, 0, 1,
            hhf, coefS, hbs, htsNxt, nullptr, nullptr);
        u16* tmp = htsCur; htsCur = htsNxt; htsNxt = tmp;
    }

    final_kernel<<<ROWS, 256, 0, stream>>>(x, h, hhf, Pp, mode_logit, residual_gate,
                                           ln_post_g, ln_post_b, out);
}